// Round 3
// baseline (1505.260 us; speedup 1.0000x reference)
//
#include <hip/hip_runtime.h>
#include <hip/hip_bf16.h>

// CPCA_Weighted: T=256 N=8 H=512 K=16 A=4, 7 actions, P_SUB=0.1, LOSS_FACTOR=0.1
// R3: cross-wg split of the GRU. 32 groups (M=64 seqs) x 8 slices (S=64 h-cols)
// = 256 wgs x 448 thr. B (W_hh) register-resident per wave, A (h) staged in LDS,
// per-step group barrier via device-scope flags, ping-pong global h buffer.
#define T_DIM 256
#define KK    16

typedef __attribute__((ext_vector_type(8))) short bf16x8;
typedef __attribute__((ext_vector_type(4))) float f32x4;

#define MFMA16(A, B, C) __builtin_amdgcn_mfma_f32_16x16x32_bf16(A, B, C, 0, 0, 0)

__device__ __forceinline__ unsigned short f2b(float x) {
  unsigned u = __float_as_uint(x);
  unsigned r = (u + 0x7FFFu + ((u >> 16) & 1u)) >> 16;   // RNE
  return (unsigned short)r;
}

// JAX threefry2x32 (20 rounds)
__device__ __forceinline__ void tf2x32(unsigned k0, unsigned k1, unsigned x0, unsigned x1,
                                       unsigned &o0, unsigned &o1) {
  unsigned ks2 = k0 ^ k1 ^ 0x1BD11BDAu;
  x0 += k0; x1 += k1;
#define TFR(R) { x0 += x1; x1 = (x1 << R) | (x1 >> (32 - R)); x1 ^= x0; }
  TFR(13) TFR(15) TFR(26) TFR(6)   x0 += k1;  x1 += ks2 + 1u;
  TFR(17) TFR(29) TFR(16) TFR(24)  x0 += ks2; x1 += k0 + 2u;
  TFR(13) TFR(15) TFR(26) TFR(6)   x0 += k0;  x1 += k1 + 3u;
  TFR(17) TFR(29) TFR(16) TFR(24)  x0 += k1;  x1 += ks2 + 4u;
  TFR(13) TFR(15) TFR(26) TFR(6)   x0 += ks2; x1 += k0 + 5u;
#undef TFR
  o0 = x0; o1 = x1;
}

// ---------------- prep: all tables, swizzles, masks, flag/accum zero ----------
__global__ void prep(const float* __restrict__ W_hh, const float* __restrict__ W1,
                     const float* __restrict__ emb,  const float* __restrict__ W_ih,
                     const float* __restrict__ b_ih, const float* __restrict__ b_hh,
                     const float* __restrict__ vision, const int* __restrict__ env_zeros,
                     unsigned short* __restrict__ wBf, unsigned short* __restrict__ wQf,
                     float* __restrict__ girz, float* __restrict__ gin,
                     float* __restrict__ projP, unsigned char* __restrict__ maskb,
                     float* __restrict__ accum, int* __restrict__ gflag) {
  int b = blockIdx.x, tid = threadIdx.x;
  if (b < 3072) {                              // wBf: [sl(8)][nu(12)][kt(16)] B-frags
    int idx = b * 256 + tid;
    int e = idx & 7, l = (idx >> 3) & 63;
    int F = idx >> 9;
    int kt = F & 15, snu = F >> 4;
    int nu = snu % 12, sl = snu / 12;
    int gam = nu >> 2, q = nu & 3;
    int ncol = gam * 512 + sl * 64 + q * 16 + (l & 15);
    int k = kt * 32 + (l >> 4) * 8 + e;
    wBf[idx] = f2b(W_hh[(size_t)ncol * 512 + k]);
  } else if (b < 3136) {                       // wQf: [ft(2)][kt(16)] cls B-frags
    int idx = (b - 3072) * 256 + tid;
    int e = idx & 7, l = (idx >> 3) & 63;
    int F = idx >> 9;
    int kt = F & 15, ft = F >> 4;
    int f = ft * 16 + (l & 15);
    int k = kt * 32 + (l >> 4) * 8 + e;
    wQf[idx] = f2b(W1[(size_t)f * 1024 + 512 + k]);
  } else if (b < 3168) {                       // girz[gam*8+a][512] = b_ih+b_hh+emb@W_ih
    int idx = (b - 3136) * 256 + tid;
    int c = idx & 511, ga = idx >> 9;
    int a = ga & 7, gam = ga >> 3;
    float s = b_ih[gam * 512 + c] + b_hh[gam * 512 + c];
    if (a < 7) {
      #pragma unroll
      for (int k = 0; k < 4; ++k) s += emb[a * 4 + k] * W_ih[(gam * 512 + c) * 4 + k];
    }
    girz[idx] = s;
  } else if (b < 3184) {                       // gin[a][512] = i_n (no b_hh!)
    int idx = (b - 3168) * 256 + tid;
    int c = idx & 511, a = idx >> 9;
    float s = b_ih[1024 + c];
    if (a < 7) {
      #pragma unroll
      for (int k = 0; k < 4; ++k) s += emb[a * 4 + k] * W_ih[(1024 + c) * 4 + k];
    }
    gin[idx] = s;
  } else if (b < 3440) {                       // projP[s][f] = vision[s] . W1a[f]
    int e = (b - 3184) * 256 + tid;
    int s = e >> 5, f = e & 31;
    const float4* vr = (const float4*)(vision + (size_t)s * 512);
    const float4* wr = (const float4*)(W1 + (size_t)f * 1024);
    float acc = 0.f;
    for (int i = 0; i < 128; ++i) {
      float4 a = vr[i], w = wr[i];
      acc += a.x * w.x + a.y * w.y + a.z * w.z + a.w * w.w;
    }
    projP[e] = acc;
  } else if (b < 3504) {                       // masks: legacy JAX threefry
    int i = (b - 3440) * 256 + tid;            // [0,16384)
    unsigned a0, b0, a1, b1_;
    tf2x32(0u, 42u, 0u, 2u, a0, b0);
    tf2x32(0u, 42u, 1u, 3u, a1, b1_);
    unsigned p0, p1, n0, n1;
    tf2x32(a0, a1, (unsigned)i, (unsigned)(i + 16384), p0, p1);
    tf2x32(b0, b1_, (unsigned)i, (unsigned)(i + 16384), n0, n1);
    #pragma unroll
    for (int h = 0; h < 2; ++h) {
      int f = i + h * 16384;
      unsigned pw = h ? p1 : p0, nw = h ? n1 : n0;
      int t = f >> 7, j = (f >> 3) & 15, nn = f & 7;
      int ok = (t + j < T_DIM - 1);
      if (ok) {
        int lo = t + 1, hi = t + j + 1, hit = 0;
        #pragma unroll
        for (int q = 0; q < 4; ++q) { int z = env_zeros[nn * 4 + q]; hit |= (z >= lo && z <= hi); }
        ok = !hit;
      }
      unsigned sp = ((pw >> 9) < 0xCCCCDu) ? 1u : 0u;
      unsigned sn = ((nw >> 9) < 0xCCCCDu) ? 2u : 0u;
      maskb[f] = ok ? (unsigned char)(sp | sn) : (unsigned char)0;
    }
  } else {                                     // zero accum + flags
    if (tid < 4) accum[tid] = 0.f;
    if (tid < 256) gflag[tid] = 0;
  }
}

// ---------------- main persistent GRU ----------------------------------------
__global__ __launch_bounds__(448, 2) void gru_main(
    const float* __restrict__ belief, const int* __restrict__ actions,
    const int* __restrict__ neg_inds,
    const float* __restrict__ b1, const float* __restrict__ W2, const float* __restrict__ b2,
    const float* __restrict__ b_hh,
    const unsigned short* __restrict__ wBf, const unsigned short* __restrict__ wQf,
    const float* __restrict__ girz, const float* __restrict__ gin,
    const float* __restrict__ projP, const unsigned char* __restrict__ maskb,
    unsigned short* __restrict__ hbuf, int* __restrict__ gflag,
    float* __restrict__ accum) {
  __shared__ char smem[65536];
  unsigned short* sA = (unsigned short*)smem;                 // 64 frags x 512 sh (64KB)
  float* accL = (float*)smem;                                 // alias: 8x4x64x4 f32 (32KB)
  unsigned short* bounce = (unsigned short*)(smem + 32768);   // alias: [64][72] ushort

  const int tid = threadIdx.x, w = tid >> 6, lane = tid & 63;
  const int b = blockIdx.x;
  const int sl = b >> 5, g = b & 31;           // b%8 == g%8 -> group on one XCD (if RR)
  const int c0 = sl * 64;
  const int seqbase = g * 64;
  const int col0 = lane & 15, quad = lane >> 4;

  // B fragments: 2 N-tiles per wave, register-resident for all 16 steps
  bf16x8 bB0[16], bB1[16];
  {
    const unsigned short* p0 = (w < 6)
        ? wBf + ((size_t)((sl * 12 + 2 * w) * 16) << 9) + lane * 8
        : wQf + lane * 8;
    #pragma unroll
    for (int kt = 0; kt < 16; ++kt) {
      bB0[kt] = *(const bf16x8*)(p0 + (kt << 9));
      bB1[kt] = *(const bf16x8*)(p0 + ((16 + kt) << 9));
    }
  }

  // fp32 h carry for the n-gate waves (w=4,5): their D-tile positions
  const int half = w - 4;
  f32x4 hp[4][2];
  if (w == 4 || w == 5) {
    #pragma unroll
    for (int a = 0; a < 4; ++a)
      #pragma unroll
      for (int t2 = 0; t2 < 2; ++t2) {
        int cc = c0 + half * 32 + t2 * 16 + col0;
        #pragma unroll
        for (int r = 0; r < 4; ++r) {
          int seq = seqbase + 16 * a + quad * 4 + r;
          hp[a][t2][r] = belief[(size_t)seq * 512 + cc];
        }
      }
  }

  // stage0: belief -> sA in A-frag layout
  for (int idx = tid; idx < 4096; idx += 448) {
    int f = idx >> 6, l = idx & 63;
    int a = f >> 4, kt = f & 15;
    int seq = seqbase + a * 16 + (l & 15);
    int kb = kt * 32 + (l >> 4) * 8;
    const float* src = belief + (size_t)seq * 512 + kb;
    float4 v0 = *(const float4*)src, v1 = *(const float4*)(src + 4);
    bf16x8 o;
    o[0] = (short)f2b(v0.x); o[1] = (short)f2b(v0.y); o[2] = (short)f2b(v0.z); o[3] = (short)f2b(v0.w);
    o[4] = (short)f2b(v1.x); o[5] = (short)f2b(v1.y); o[6] = (short)f2b(v1.z); o[7] = (short)f2b(v1.w);
    *(bf16x8*)&sA[f * 512 + l * 8] = o;
  }
  __syncthreads();

  // cls-wave constants
  float b1v0 = 0.f, b1v1 = 0.f, w2v0 = 0.f, w2v1 = 0.f, b2v = 0.f;
  if (w == 6) { b1v0 = b1[col0]; b1v1 = b1[col0 + 16]; w2v0 = W2[col0]; w2v1 = W2[col0 + 16]; b2v = b2[0]; }
  float sumP = 0.f, cntP = 0.f, sumN = 0.f, cntN = 0.f;

  for (int j = 0; j <= KK; ++j) {
    f32x4 acc[4][2];
    #pragma unroll
    for (int a = 0; a < 4; ++a)
      #pragma unroll
      for (int t2 = 0; t2 < 2; ++t2) acc[a][t2] = (f32x4){0.f, 0.f, 0.f, 0.f};

    bool doG = (w < 6) ? (j < KK) : (j > 0);
    if (doG) {
      #pragma unroll
      for (int kt = 0; kt < 16; ++kt) {
        #pragma unroll
        for (int a = 0; a < 4; ++a) {
          bf16x8 af = *(const bf16x8*)&sA[(a * 16 + kt) * 512 + lane * 8];
          acc[a][0] = MFMA16(af, bB0[kt], acc[a][0]);
          acc[a][1] = MFMA16(af, bB1[kt], acc[a][1]);
        }
      }
    }

    if (w == 6 && j > 0) {                     // classifier + loss for jq = j-1
      const int jq = j - 1;
      float wj = (jq == 0) ? 5.f : (jq == 1) ? 4.f : (jq < 4) ? 3.f : (jq < 8) ? 2.f : 1.f;
      #pragma unroll
      for (int a = 0; a < 4; ++a)
        #pragma unroll
        for (int r = 0; r < 4; ++r) {
          int seq = seqbase + 16 * a + quad * 4 + r;
          int t = seq >> 3, nn = seq & 7;
          unsigned mb = maskb[(t << 7) + (jq << 3) + nn];
          float pp0 = 0.f, pp1 = 0.f, pn0 = 0.f, pn1 = 0.f;
          if (mb) {
            int sp = seq + j * 8;
            pp0 = projP[(sp << 5) + col0];  pp1 = projP[(sp << 5) + 16 + col0];
            int ni = neg_inds[sp];
            pn0 = projP[(ni << 5) + col0];  pn1 = projP[(ni << 5) + 16 + col0];
          }
          float a0v = acc[a][0][r] + b1v0, a1v = acc[a][1][r] + b1v1;
          float pl = fmaxf(a0v + pp0, 0.f) * w2v0 + fmaxf(a1v + pp1, 0.f) * w2v1;
          float nl = fmaxf(a0v + pn0, 0.f) * w2v0 + fmaxf(a1v + pn1, 0.f) * w2v1;
          #pragma unroll
          for (int d = 1; d < 16; d <<= 1) {
            pl += __shfl_xor(pl, d, 64);
            nl += __shfl_xor(nl, d, 64);
          }
          if (col0 == 0 && mb) {
            if (mb & 1u) {
              float x = -(pl + b2v);
              sumP += wj * (fmaxf(x, 0.f) + __logf(1.f + __expf(-fabsf(x))));
              cntP += 1.f;
            }
            if (mb & 2u) {
              float x = (nl + b2v);
              sumN += wj * (fmaxf(x, 0.f) + __logf(1.f + __expf(-fabsf(x))));
              cntN += 1.f;
            }
          }
        }
    }
    if (j == KK) break;
    __syncthreads();

    // phase B: r,z waves publish accs to LDS (alias over dead A-frags)
    if (w < 4) {
      #pragma unroll
      for (int t2 = 0; t2 < 2; ++t2)
        #pragma unroll
        for (int a = 0; a < 4; ++a) {
          int nu = 2 * w + t2;
          *(f32x4*)&accL[((nu * 4 + a) * 64 + lane) * 4] = acc[a][t2];
        }
    }
    __syncthreads();

    // phase C: n-gate waves do the full GRU epilogue for their 32-col half
    if (w == 4 || w == 5) {
      #pragma unroll
      for (int t2 = 0; t2 < 2; ++t2) {
        int q = half * 2 + t2;
        int cc = c0 + half * 32 + t2 * 16 + col0;
        float bhhn = b_hh[1024 + cc];
        #pragma unroll
        for (int a = 0; a < 4; ++a) {
          f32x4 aR = *(const f32x4*)&accL[((q * 4 + a) * 64 + lane) * 4];
          f32x4 aZ = *(const f32x4*)&accL[(((4 + q) * 4 + a) * 64 + lane) * 4];
          #pragma unroll
          for (int r = 0; r < 4; ++r) {
            int row = quad * 4 + r;
            int seq = seqbase + 16 * a + row;
            int t = seq >> 3, nn = seq & 7, tj = t + j;
            int ai = (tj < T_DIM) ? actions[tj * 8 + nn] : 7;
            float rg = 1.f / (1.f + __expf(-(aR[r] + girz[(ai << 9) + cc])));
            float zg = 1.f / (1.f + __expf(-(aZ[r] + girz[((8 + ai) << 9) + cc])));
            float pre = gin[(ai << 9) + cc] + rg * (acc[a][t2][r] + bhhn);
            float cand = 1.f - 2.f / (1.f + __expf(2.f * pre));
            float hn = (1.f - zg) * cand + zg * hp[a][t2][r];
            hp[a][t2][r] = hn;
            bounce[(16 * a + row) * 72 + half * 32 + t2 * 16 + col0] = f2b(hn);
          }
        }
      }
    }
    __syncthreads();

    // phase D: transpose-store our 8 frags to the ping-pong global h buffer
    const int slot = (j + 1) & 1;
    const size_t sbase = (size_t)slot * 1048576;
    for (int idx = tid; idx < 512; idx += 448) {
      int f = idx >> 6, l = idx & 63;
      int a = f >> 1, ktl = f & 1;
      bf16x8 v = *(const bf16x8*)&bounce[(16 * a + (l & 15)) * 72 + 32 * ktl + (l >> 4) * 8];
      *(bf16x8*)&hbuf[sbase + (size_t)(g * 64 + a * 16 + sl * 2 + ktl) * 512 + l * 8] = v;
    }
    __threadfence();
    __syncthreads();
    if (tid == 0) atomicExch(&gflag[g * 8 + sl], j + 1);
    // phase E: group barrier — all 8 slices of this group done with step j
    if (tid < 8) {
      while (atomicAdd(&gflag[g * 8 + tid], 0) < j + 1) __builtin_amdgcn_s_sleep(2);
    }
    __syncthreads();
    __threadfence();
    // phase F: stage h_{j+1} -> sA (coalesced frag loads)
    for (int idx = tid; idx < 4096; idx += 448) {
      int f = idx >> 6, l = idx & 63;
      bf16x8 v = *(const bf16x8*)&hbuf[sbase + (size_t)(g * 64 + f) * 512 + l * 8];
      *(bf16x8*)&sA[f * 512 + l * 8] = v;
    }
    __syncthreads();
  }

  if (w == 6 && col0 == 0) {
    atomicAdd(&accum[0], sumP); atomicAdd(&accum[1], cntP);
    atomicAdd(&accum[2], sumN); atomicAdd(&accum[3], cntN);
  }
}

__global__ void fin(const float* __restrict__ accum, float* __restrict__ out) {
  out[0] = (accum[0] / fmaxf(accum[1], 1.f) + accum[2] / fmaxf(accum[3], 1.f)) * 0.1f;
}

extern "C" void kernel_launch(void* const* d_in, const int* in_sizes, int n_in,
                              void* d_out, int out_size, void* d_ws, size_t ws_size,
                              hipStream_t stream) {
  const float* vision  = (const float*)d_in[0];
  const float* belief  = (const float*)d_in[1];
  const int*   actions = (const int*)d_in[2];
  const int*   envz    = (const int*)d_in[3];
  const int*   negi    = (const int*)d_in[4];
  const float* emb     = (const float*)d_in[5];
  const float* W_ih    = (const float*)d_in[6];
  const float* W_hh    = (const float*)d_in[7];
  const float* b_ih    = (const float*)d_in[8];
  const float* b_hh    = (const float*)d_in[9];
  const float* W1      = (const float*)d_in[10];
  const float* b1      = (const float*)d_in[11];
  const float* W2      = (const float*)d_in[12];
  const float* b2      = (const float*)d_in[13];

  char* ws = (char*)d_ws;
  float*          accum = (float*)(ws + 0);                  // 16 B (pad 256)
  int*            gflag = (int*)(ws + 256);                  // 1024 B
  unsigned short* wBf   = (unsigned short*)(ws + 2048);      // 1572864 B
  unsigned short* wQf   = (unsigned short*)(ws + 1574912);   // 32768 B
  float*          girz  = (float*)(ws + 1607680);            // 32768 B
  float*          gin   = (float*)(ws + 1640448);            // 16384 B
  float*          projP = (float*)(ws + 1656832);            // 262144 B
  unsigned char*  maskb = (unsigned char*)(ws + 1918976);    // 32768 B
  unsigned short* hbuf  = (unsigned short*)(ws + 1951744);   // 4194304 B (2 slots)

  prep<<<3505, 256, 0, stream>>>(W_hh, W1, emb, W_ih, b_ih, b_hh, vision, envz,
                                 wBf, wQf, girz, gin, projP, maskb, accum, gflag);
  gru_main<<<256, 448, 0, stream>>>(belief, actions, negi, b1, W2, b2, b_hh,
                                    wBf, wQf, girz, gin, projP, maskb,
                                    hbuf, gflag, accum);
  fin<<<1, 1, 0, stream>>>(accum, (float*)d_out);
}

// Round 4
// 575.187 us; speedup vs baseline: 2.6170x; 2.6170x over previous
//
#include <hip/hip_runtime.h>
#include <hip/hip_bf16.h>

// CPCA_Weighted: T=256 N=8 H=512 K=16 A=4, 7 actions, P_SUB=0.1, LOSS_FACTOR=0.1
// R4: R3's slice-split GRU (32 groups x 8 slices, B register-resident) but the
// per-step cross-wg barrier is the KERNEL BOUNDARY: 16 chained step-kernels.
#define T_DIM 256
#define KK    16

typedef __attribute__((ext_vector_type(8))) short bf16x8;
typedef __attribute__((ext_vector_type(4))) float f32x4;

#define MFMA16(A, B, C) __builtin_amdgcn_mfma_f32_16x16x32_bf16(A, B, C, 0, 0, 0)

__device__ __forceinline__ unsigned short f2b(float x) {
  unsigned u = __float_as_uint(x);
  unsigned r = (u + 0x7FFFu + ((u >> 16) & 1u)) >> 16;   // RNE
  return (unsigned short)r;
}

// JAX threefry2x32 (20 rounds)
__device__ __forceinline__ void tf2x32(unsigned k0, unsigned k1, unsigned x0, unsigned x1,
                                       unsigned &o0, unsigned &o1) {
  unsigned ks2 = k0 ^ k1 ^ 0x1BD11BDAu;
  x0 += k0; x1 += k1;
#define TFR(R) { x0 += x1; x1 = (x1 << R) | (x1 >> (32 - R)); x1 ^= x0; }
  TFR(13) TFR(15) TFR(26) TFR(6)   x0 += k1;  x1 += ks2 + 1u;
  TFR(17) TFR(29) TFR(16) TFR(24)  x0 += ks2; x1 += k0 + 2u;
  TFR(13) TFR(15) TFR(26) TFR(6)   x0 += k0;  x1 += k1 + 3u;
  TFR(17) TFR(29) TFR(16) TFR(24)  x0 += k1;  x1 += ks2 + 4u;
  TFR(13) TFR(15) TFR(26) TFR(6)   x0 += ks2; x1 += k0 + 5u;
#undef TFR
  o0 = x0; o1 = x1;
}

// ---------------- prep: tables, swizzles, masks, hb0 staging, accum zero ------
__global__ void prep(const float* __restrict__ W_hh, const float* __restrict__ W1,
                     const float* __restrict__ emb,  const float* __restrict__ W_ih,
                     const float* __restrict__ b_ih, const float* __restrict__ b_hh,
                     const float* __restrict__ vision, const int* __restrict__ env_zeros,
                     const float* __restrict__ belief,
                     unsigned short* __restrict__ wBf, unsigned short* __restrict__ wQf,
                     float* __restrict__ girz, float* __restrict__ gin,
                     float* __restrict__ projP, unsigned char* __restrict__ maskb,
                     unsigned short* __restrict__ hb0, float* __restrict__ accum) {
  int b = blockIdx.x, tid = threadIdx.x;
  if (b < 3072) {                              // wBf: [sl(8)][nu(12)][kt(16)] B-frags
    int idx = b * 256 + tid;
    int e = idx & 7, l = (idx >> 3) & 63;
    int F = idx >> 9;
    int kt = F & 15, snu = F >> 4;
    int nu = snu % 12, sl = snu / 12;
    int gam = nu >> 2, q = nu & 3;
    int ncol = gam * 512 + sl * 64 + q * 16 + (l & 15);
    int k = kt * 32 + (l >> 4) * 8 + e;
    wBf[idx] = f2b(W_hh[(size_t)ncol * 512 + k]);
  } else if (b < 3136) {                       // wQf: [ft(2)][kt(16)] cls B-frags
    int idx = (b - 3072) * 256 + tid;
    int e = idx & 7, l = (idx >> 3) & 63;
    int F = idx >> 9;
    int kt = F & 15, ft = F >> 4;
    int f = ft * 16 + (l & 15);
    int k = kt * 32 + (l >> 4) * 8 + e;
    wQf[idx] = f2b(W1[(size_t)f * 1024 + 512 + k]);
  } else if (b < 3168) {                       // girz[gam*8+a][512]
    int idx = (b - 3136) * 256 + tid;
    int c = idx & 511, ga = idx >> 9;
    int a = ga & 7, gam = ga >> 3;
    float s = b_ih[gam * 512 + c] + b_hh[gam * 512 + c];
    if (a < 7) {
      #pragma unroll
      for (int k = 0; k < 4; ++k) s += emb[a * 4 + k] * W_ih[(gam * 512 + c) * 4 + k];
    }
    girz[idx] = s;
  } else if (b < 3184) {                       // gin[a][512] = i_n (no b_hh)
    int idx = (b - 3168) * 256 + tid;
    int c = idx & 511, a = idx >> 9;
    float s = b_ih[1024 + c];
    if (a < 7) {
      #pragma unroll
      for (int k = 0; k < 4; ++k) s += emb[a * 4 + k] * W_ih[(1024 + c) * 4 + k];
    }
    gin[idx] = s;
  } else if (b < 3440) {                       // projP[s][f] = vision[s] . W1a[f]
    int e = (b - 3184) * 256 + tid;
    int s = e >> 5, f = e & 31;
    const float4* vr = (const float4*)(vision + (size_t)s * 512);
    const float4* wr = (const float4*)(W1 + (size_t)f * 1024);
    float acc = 0.f;
    for (int i = 0; i < 128; ++i) {
      float4 a = vr[i], w = wr[i];
      acc += a.x * w.x + a.y * w.y + a.z * w.z + a.w * w.w;
    }
    projP[e] = acc;
  } else if (b < 3504) {                       // masks: legacy JAX threefry
    int i = (b - 3440) * 256 + tid;
    unsigned a0, b0, a1, b1_;
    tf2x32(0u, 42u, 0u, 2u, a0, b0);
    tf2x32(0u, 42u, 1u, 3u, a1, b1_);
    unsigned p0, p1, n0, n1;
    tf2x32(a0, a1, (unsigned)i, (unsigned)(i + 16384), p0, p1);
    tf2x32(b0, b1_, (unsigned)i, (unsigned)(i + 16384), n0, n1);
    #pragma unroll
    for (int h = 0; h < 2; ++h) {
      int f = i + h * 16384;
      unsigned pw = h ? p1 : p0, nw = h ? n1 : n0;
      int t = f >> 7, j = (f >> 3) & 15, nn = f & 7;
      int ok = (t + j < T_DIM - 1);
      if (ok) {
        int lo = t + 1, hi = t + j + 1, hit = 0;
        #pragma unroll
        for (int q = 0; q < 4; ++q) { int z = env_zeros[nn * 4 + q]; hit |= (z >= lo && z <= hi); }
        ok = !hit;
      }
      unsigned sp = ((pw >> 9) < 0xCCCCDu) ? 1u : 0u;
      unsigned sn = ((nw >> 9) < 0xCCCCDu) ? 2u : 0u;
      maskb[f] = ok ? (unsigned char)(sp | sn) : (unsigned char)0;
    }
  } else if (b == 3504) {
    if (tid < 4) accum[tid] = 0.f;
  } else {                                     // hb0: belief -> A-frag layout
    int i = (b - 3505) * 256 + tid;            // [0, 131072)
    int f = i >> 6, l = i & 63;
    int seq = (f >> 4) * 16 + (l & 15);
    int kb = (f & 15) * 32 + (l >> 4) * 8;
    const float* src = belief + (size_t)seq * 512 + kb;
    float4 v0 = *(const float4*)src, v1 = *(const float4*)(src + 4);
    bf16x8 o;
    o[0] = (short)f2b(v0.x); o[1] = (short)f2b(v0.y); o[2] = (short)f2b(v0.z); o[3] = (short)f2b(v0.w);
    o[4] = (short)f2b(v1.x); o[5] = (short)f2b(v1.y); o[6] = (short)f2b(v1.z); o[7] = (short)f2b(v1.w);
    *(bf16x8*)&hb0[(size_t)f * 512 + l * 8] = o;
  }
}

// ---------------- one GRU step (kernel boundary = device barrier) -------------
__global__ __launch_bounds__(448, 1) void gru_step(
    int j, const float* __restrict__ hFin, float* __restrict__ hFout,
    const unsigned short* __restrict__ hbin, unsigned short* __restrict__ hbout,
    const int* __restrict__ actions, const int* __restrict__ neg_inds,
    const float* __restrict__ b1, const float* __restrict__ W2, const float* __restrict__ b2,
    const float* __restrict__ b_hh,
    const unsigned short* __restrict__ wBf, const unsigned short* __restrict__ wQf,
    const float* __restrict__ girz, const float* __restrict__ gin,
    const float* __restrict__ projP, const unsigned char* __restrict__ maskb,
    float* __restrict__ accum) {
  __shared__ char smem[65536];
  unsigned short* sA = (unsigned short*)smem;                 // 64 frags x 1KB
  float* accL = (float*)smem;                                 // alias (after GEMM)
  unsigned short* bounce = (unsigned short*)(smem + 32768);   // alias: [64][72]

  const int tid = threadIdx.x, w = tid >> 6, lane = tid & 63;
  const int b = blockIdx.x;
  const int sl = b >> 5, g = b & 31;
  const int c0 = sl * 64;
  const int seqbase = g * 64;
  const int col0 = lane & 15, quad = lane >> 4;
  const int half = w - 4;

  // B fragments: 2 N-tiles, register-resident (loaded once per kernel)
  bf16x8 bB0[16], bB1[16];
  {
    const unsigned short* p0 = (w < 6)
        ? wBf + ((size_t)((sl * 12 + 2 * w) * 16) << 9) + lane * 8
        : wQf + lane * 8;
    #pragma unroll
    for (int kt = 0; kt < 16; ++kt) {
      bB0[kt] = *(const bf16x8*)(p0 + (kt << 9));
      bB1[kt] = *(const bf16x8*)(p0 + ((16 + kt) << 9));
    }
  }

  // fp32 h carry for the n-gate waves (w=4,5)
  f32x4 hp[4][2];
  if (w == 4 || w == 5) {
    #pragma unroll
    for (int a = 0; a < 4; ++a)
      #pragma unroll
      for (int t2 = 0; t2 < 2; ++t2) {
        int cc = c0 + half * 32 + t2 * 16 + col0;
        #pragma unroll
        for (int r = 0; r < 4; ++r) {
          int seq = seqbase + 16 * a + quad * 4 + r;
          hp[a][t2][r] = hFin[(size_t)seq * 512 + cc];
        }
      }
  }

  // stage A: hbin -> LDS (coalesced frag loads)
  for (int idx = tid; idx < 4096; idx += 448) {
    int f = idx >> 6, l = idx & 63;
    bf16x8 v = *(const bf16x8*)&hbin[((size_t)(g * 64 + f) << 9) + l * 8];
    *(bf16x8*)&sA[f * 512 + l * 8] = v;
  }
  __syncthreads();

  f32x4 acc[4][2];
  #pragma unroll
  for (int a = 0; a < 4; ++a)
    #pragma unroll
    for (int t2 = 0; t2 < 2; ++t2) acc[a][t2] = (f32x4){0.f, 0.f, 0.f, 0.f};

  const bool clsOn = (w == 6) && (j > 0) && (sl == 0);
  if (w < 6 || clsOn) {
    #pragma unroll
    for (int kt = 0; kt < 16; ++kt) {
      #pragma unroll
      for (int a = 0; a < 4; ++a) {
        bf16x8 af = *(const bf16x8*)&sA[(a * 16 + kt) * 512 + lane * 8];
        acc[a][0] = MFMA16(af, bB0[kt], acc[a][0]);
        acc[a][1] = MFMA16(af, bB1[kt], acc[a][1]);
      }
    }
  }
  __syncthreads();   // sA reads complete; accL/bounce alias becomes live

  if (clsOn) {                                 // classifier + loss for jq = j-1
    const int jq = j - 1;
    float b1v0 = b1[col0], b1v1 = b1[col0 + 16];
    float w2v0 = W2[col0], w2v1 = W2[col0 + 16], b2v = b2[0];
    float wj = (jq == 0) ? 5.f : (jq == 1) ? 4.f : (jq < 4) ? 3.f : (jq < 8) ? 2.f : 1.f;
    float sumP = 0.f, cntP = 0.f, sumN = 0.f, cntN = 0.f;
    #pragma unroll
    for (int a = 0; a < 4; ++a)
      #pragma unroll
      for (int r = 0; r < 4; ++r) {
        int seq = seqbase + 16 * a + quad * 4 + r;
        int t = seq >> 3, nn = seq & 7;
        unsigned mb = maskb[(t << 7) + (jq << 3) + nn];
        float pp0 = 0.f, pp1 = 0.f, pn0 = 0.f, pn1 = 0.f;
        if (mb) {
          int sp = seq + j * 8;
          pp0 = projP[(sp << 5) + col0];  pp1 = projP[(sp << 5) + 16 + col0];
          int ni = neg_inds[sp];
          pn0 = projP[(ni << 5) + col0];  pn1 = projP[(ni << 5) + 16 + col0];
        }
        float a0v = acc[a][0][r] + b1v0, a1v = acc[a][1][r] + b1v1;
        float pl = fmaxf(a0v + pp0, 0.f) * w2v0 + fmaxf(a1v + pp1, 0.f) * w2v1;
        float nl = fmaxf(a0v + pn0, 0.f) * w2v0 + fmaxf(a1v + pn1, 0.f) * w2v1;
        #pragma unroll
        for (int d = 1; d < 16; d <<= 1) {
          pl += __shfl_xor(pl, d, 64);
          nl += __shfl_xor(nl, d, 64);
        }
        if (col0 == 0 && mb) {
          if (mb & 1u) {
            float x = -(pl + b2v);
            sumP += wj * (fmaxf(x, 0.f) + __logf(1.f + __expf(-fabsf(x))));
            cntP += 1.f;
          }
          if (mb & 2u) {
            float x = (nl + b2v);
            sumN += wj * (fmaxf(x, 0.f) + __logf(1.f + __expf(-fabsf(x))));
            cntN += 1.f;
          }
        }
      }
    if (col0 == 0) {
      atomicAdd(&accum[0], sumP); atomicAdd(&accum[1], cntP);
      atomicAdd(&accum[2], sumN); atomicAdd(&accum[3], cntN);
    }
  }

  // phase B: r,z waves publish accs to LDS
  if (w < 4) {
    #pragma unroll
    for (int t2 = 0; t2 < 2; ++t2)
      #pragma unroll
      for (int a = 0; a < 4; ++a) {
        int nu = 2 * w + t2;
        *(f32x4*)&accL[((nu * 4 + a) * 64 + lane) * 4] = acc[a][t2];
      }
  }
  __syncthreads();

  // phase C: n-gate waves do the GRU epilogue for their 32-col half
  if (w == 4 || w == 5) {
    #pragma unroll
    for (int t2 = 0; t2 < 2; ++t2) {
      int q = half * 2 + t2;
      int cc = c0 + half * 32 + t2 * 16 + col0;
      float bhhn = b_hh[1024 + cc];
      #pragma unroll
      for (int a = 0; a < 4; ++a) {
        f32x4 aR = *(const f32x4*)&accL[((q * 4 + a) * 64 + lane) * 4];
        f32x4 aZ = *(const f32x4*)&accL[(((4 + q) * 4 + a) * 64 + lane) * 4];
        #pragma unroll
        for (int r = 0; r < 4; ++r) {
          int row = quad * 4 + r;
          int seq = seqbase + 16 * a + row;
          int t = seq >> 3, nn = seq & 7, tj = t + j;
          int ai = (tj < T_DIM) ? actions[tj * 8 + nn] : 7;
          float rg = 1.f / (1.f + __expf(-(aR[r] + girz[(ai << 9) + cc])));
          float zg = 1.f / (1.f + __expf(-(aZ[r] + girz[((8 + ai) << 9) + cc])));
          float pre = gin[(ai << 9) + cc] + rg * (acc[a][t2][r] + bhhn);
          float cand = 1.f - 2.f / (1.f + __expf(2.f * pre));
          float hn = (1.f - zg) * cand + zg * hp[a][t2][r];
          hFout[(size_t)seq * 512 + cc] = hn;
          bounce[(16 * a + row) * 72 + half * 32 + t2 * 16 + col0] = f2b(hn);
        }
      }
    }
  }
  __syncthreads();

  // phase D: coalesced frag store of our slice to hbout
  for (int idx = tid; idx < 512; idx += 448) {
    int f = idx >> 6, l = idx & 63;
    int a = f >> 1, ktl = f & 1;
    bf16x8 v = *(const bf16x8*)&bounce[(16 * a + (l & 15)) * 72 + 32 * ktl + (l >> 4) * 8];
    *(bf16x8*)&hbout[((size_t)(g * 64 + a * 16 + sl * 2 + ktl) << 9) + l * 8] = v;
  }
}

// ---------------- cls for jq=15 (reads h_16 frags directly from global) -------
__global__ __launch_bounds__(64, 1) void cls16(
    const unsigned short* __restrict__ hb, const unsigned short* __restrict__ wQf,
    const int* __restrict__ neg_inds,
    const float* __restrict__ b1, const float* __restrict__ W2, const float* __restrict__ b2,
    const float* __restrict__ projP, const unsigned char* __restrict__ maskb,
    float* __restrict__ accum) {
  const int g = blockIdx.x, lane = threadIdx.x;
  const int col0 = lane & 15, quad = lane >> 4;
  const int seqbase = g * 64;
  const int jq = 15, j = 16;

  f32x4 acc[4][2];
  #pragma unroll
  for (int a = 0; a < 4; ++a) { acc[a][0] = (f32x4){0,0,0,0}; acc[a][1] = (f32x4){0,0,0,0}; }
  const unsigned short* qp = wQf + lane * 8;
  for (int kt = 0; kt < 16; ++kt) {
    bf16x8 bq0 = *(const bf16x8*)(qp + (kt << 9));
    bf16x8 bq1 = *(const bf16x8*)(qp + ((16 + kt) << 9));
    #pragma unroll
    for (int a = 0; a < 4; ++a) {
      bf16x8 af = *(const bf16x8*)&hb[((size_t)(g * 64 + a * 16 + kt) << 9) + lane * 8];
      acc[a][0] = MFMA16(af, bq0, acc[a][0]);
      acc[a][1] = MFMA16(af, bq1, acc[a][1]);
    }
  }
  float b1v0 = b1[col0], b1v1 = b1[col0 + 16];
  float w2v0 = W2[col0], w2v1 = W2[col0 + 16], b2v = b2[0];
  float sumP = 0.f, cntP = 0.f, sumN = 0.f, cntN = 0.f;
  #pragma unroll
  for (int a = 0; a < 4; ++a)
    #pragma unroll
    for (int r = 0; r < 4; ++r) {
      int seq = seqbase + 16 * a + quad * 4 + r;
      int t = seq >> 3, nn = seq & 7;
      unsigned mb = maskb[(t << 7) + (jq << 3) + nn];
      float pp0 = 0.f, pp1 = 0.f, pn0 = 0.f, pn1 = 0.f;
      if (mb) {
        int sp = seq + j * 8;
        pp0 = projP[(sp << 5) + col0];  pp1 = projP[(sp << 5) + 16 + col0];
        int ni = neg_inds[sp];
        pn0 = projP[(ni << 5) + col0];  pn1 = projP[(ni << 5) + 16 + col0];
      }
      float a0v = acc[a][0][r] + b1v0, a1v = acc[a][1][r] + b1v1;
      float pl = fmaxf(a0v + pp0, 0.f) * w2v0 + fmaxf(a1v + pp1, 0.f) * w2v1;
      float nl = fmaxf(a0v + pn0, 0.f) * w2v0 + fmaxf(a1v + pn1, 0.f) * w2v1;
      #pragma unroll
      for (int d = 1; d < 16; d <<= 1) {
        pl += __shfl_xor(pl, d, 64);
        nl += __shfl_xor(nl, d, 64);
      }
      if (col0 == 0 && mb) {
        if (mb & 1u) {
          float x = -(pl + b2v);
          sumP += (fmaxf(x, 0.f) + __logf(1.f + __expf(-fabsf(x))));  // wj = 1
          cntP += 1.f;
        }
        if (mb & 2u) {
          float x = (nl + b2v);
          sumN += (fmaxf(x, 0.f) + __logf(1.f + __expf(-fabsf(x))));
          cntN += 1.f;
        }
      }
    }
  if (col0 == 0) {
    atomicAdd(&accum[0], sumP); atomicAdd(&accum[1], cntP);
    atomicAdd(&accum[2], sumN); atomicAdd(&accum[3], cntN);
  }
}

__global__ void fin(const float* __restrict__ accum, float* __restrict__ out) {
  out[0] = (accum[0] / fmaxf(accum[1], 1.f) + accum[2] / fmaxf(accum[3], 1.f)) * 0.1f;
}

extern "C" void kernel_launch(void* const* d_in, const int* in_sizes, int n_in,
                              void* d_out, int out_size, void* d_ws, size_t ws_size,
                              hipStream_t stream) {
  const float* vision  = (const float*)d_in[0];
  const float* belief  = (const float*)d_in[1];
  const int*   actions = (const int*)d_in[2];
  const int*   envz    = (const int*)d_in[3];
  const int*   negi    = (const int*)d_in[4];
  const float* emb     = (const float*)d_in[5];
  const float* W_ih    = (const float*)d_in[6];
  const float* W_hh    = (const float*)d_in[7];
  const float* b_ih    = (const float*)d_in[8];
  const float* b_hh    = (const float*)d_in[9];
  const float* W1      = (const float*)d_in[10];
  const float* b1      = (const float*)d_in[11];
  const float* W2      = (const float*)d_in[12];
  const float* b2      = (const float*)d_in[13];

  char* ws = (char*)d_ws;
  float*          accum = (float*)(ws + 0);
  unsigned short* wBf   = (unsigned short*)(ws + 256);        // 1572864 B
  unsigned short* wQf   = (unsigned short*)(ws + 1573120);    // 32768 B
  float*          girz  = (float*)(ws + 1605888);             // 32768 B
  float*          gin   = (float*)(ws + 1638656);             // 16384 B
  float*          projP = (float*)(ws + 1655040);             // 262144 B
  unsigned char*  maskb = (unsigned char*)(ws + 1917184);     // 32768 B
  unsigned short* hb0   = (unsigned short*)(ws + 1949952);    // 2097152 B
  unsigned short* hbA   = (unsigned short*)(ws + 4047104);    // 2097152 B
  unsigned short* hbB   = (unsigned short*)(ws + 6144256);    // 2097152 B
  float*          hF    = (float*)(ws + 8241408);             // 4194304 B

  prep<<<4017, 256, 0, stream>>>(W_hh, W1, emb, W_ih, b_ih, b_hh, vision, envz,
                                 belief, wBf, wQf, girz, gin, projP, maskb, hb0, accum);
  for (int j = 0; j < 16; ++j) {
    const unsigned short* in = (j == 0) ? hb0 : ((j & 1) ? hbA : hbB);
    unsigned short* out = (j & 1) ? hbB : hbA;
    const float* hin = (j == 0) ? belief : hF;
    gru_step<<<256, 448, 0, stream>>>(j, hin, hF, in, out, actions, negi,
                                      b1, W2, b2, b_hh, wBf, wQf, girz, gin,
                                      projP, maskb, accum);
  }
  cls16<<<32, 64, 0, stream>>>(hbB, wQf, negi, b1, W2, b2, projP, maskb, accum);
  fin<<<1, 1, 0, stream>>>(accum, (float*)d_out);
}

// Round 5
// 522.247 us; speedup vs baseline: 2.8823x; 1.1014x over previous
//
#include <hip/hip_runtime.h>
#include <hip/hip_bf16.h>

// CPCA_Weighted: T=256 N=8 H=512 K=16 A=4, 7 actions, P_SUB=0.1, LOSS_FACTOR=0.1
// R5: persistent gru (256 wgs x 448thr, 1 wg/CU via 96KB LDS), B reg-resident
// (asm loads), cross-wg h exchange + group barrier via sc0/sc1 L3-direct ops.
#define T_DIM 256
#define KK    16

typedef __attribute__((ext_vector_type(8))) short bf16x8;
typedef __attribute__((ext_vector_type(4))) float f32x4;

#define MFMA16(A, B, C) __builtin_amdgcn_mfma_f32_16x16x32_bf16(A, B, C, 0, 0, 0)

__device__ __forceinline__ unsigned short f2b(float x) {
  unsigned u = __float_as_uint(x);
  unsigned r = (u + 0x7FFFu + ((u >> 16) & 1u)) >> 16;   // RNE
  return (unsigned short)r;
}

// ---- L3-direct (bypass L1+L2) ops for cross-wg communication ----------------
__device__ __forceinline__ bf16x8 ld_b128_bypass(const unsigned short* p) {
  bf16x8 r;
  asm volatile("global_load_dwordx4 %0, %1, off sc0 sc1" : "=v"(r) : "v"(p) : "memory");
  return r;
}
__device__ __forceinline__ void st_b128_bypass(unsigned short* p, bf16x8 v) {
  asm volatile("global_store_dwordx4 %0, %1, off sc0 sc1" :: "v"(p), "v"(v) : "memory");
}
__device__ __forceinline__ unsigned ld_u32_bypass(const unsigned* p) {
  unsigned r;
  asm volatile("global_load_dword %0, %1, off sc0 sc1\n\ts_waitcnt vmcnt(0)"
               : "=v"(r) : "v"(p) : "memory");
  return r;
}
// plain asm load: forces the result to stay in VGPRs (no rematerialization)
__device__ __forceinline__ bf16x8 ld_b128(const unsigned short* p) {
  bf16x8 r;
  asm volatile("global_load_dwordx4 %0, %1, off" : "=v"(r) : "v"(p) : "memory");
  return r;
}
#define WAITVM0() asm volatile("s_waitcnt vmcnt(0)" ::: "memory")

// JAX threefry2x32 (20 rounds)
__device__ __forceinline__ void tf2x32(unsigned k0, unsigned k1, unsigned x0, unsigned x1,
                                       unsigned &o0, unsigned &o1) {
  unsigned ks2 = k0 ^ k1 ^ 0x1BD11BDAu;
  x0 += k0; x1 += k1;
#define TFR(R) { x0 += x1; x1 = (x1 << R) | (x1 >> (32 - R)); x1 ^= x0; }
  TFR(13) TFR(15) TFR(26) TFR(6)   x0 += k1;  x1 += ks2 + 1u;
  TFR(17) TFR(29) TFR(16) TFR(24)  x0 += ks2; x1 += k0 + 2u;
  TFR(13) TFR(15) TFR(26) TFR(6)   x0 += k0;  x1 += k1 + 3u;
  TFR(17) TFR(29) TFR(16) TFR(24)  x0 += k1;  x1 += ks2 + 4u;
  TFR(13) TFR(15) TFR(26) TFR(6)   x0 += ks2; x1 += k0 + 5u;
#undef TFR
  o0 = x0; o1 = x1;
}

// ---- prep: coalesced-read/scattered-write swizzles, tables, masks, h0 --------
__global__ void prep(const float* __restrict__ W_hh, const float* __restrict__ W1,
                     const float* __restrict__ emb,  const float* __restrict__ W_ih,
                     const float* __restrict__ b_ih, const float* __restrict__ b_hh,
                     const float* __restrict__ vision, const int* __restrict__ env_zeros,
                     const float* __restrict__ belief,
                     unsigned short* __restrict__ wBf, unsigned short* __restrict__ wQf,
                     float* __restrict__ girz, float* __restrict__ gin,
                     float* __restrict__ projP, unsigned char* __restrict__ maskb,
                     unsigned short* __restrict__ hbS, unsigned* __restrict__ cnt,
                     float* __restrict__ accum) {
  int b = blockIdx.x, tid = threadIdx.x;
  if (b < 768) {                               // wBf swizzle: coalesced read W_hh
    int idx = b * 256 + tid;                   // handles 4 consecutive elements
    int row = idx >> 7, k4 = (idx & 127) << 2;
    float4 v = *(const float4*)(W_hh + ((size_t)row << 9) + k4);
    int gam = row >> 9, sl = (row >> 6) & 7, q = (row >> 4) & 3, col0 = row & 15;
    int kt = k4 >> 5, quad = (k4 >> 3) & 3, e = k4 & 7;
    int F = (sl * 12 + gam * 4 + q) * 16 + kt;
    ushort4 o; o.x = f2b(v.x); o.y = f2b(v.y); o.z = f2b(v.z); o.w = f2b(v.w);
    *(ushort4*)(wBf + ((size_t)F << 9) + ((quad * 16 + col0) << 3) + e) = o;
  } else if (b < 784) {                        // wQf swizzle
    int idx = (b - 768) * 256 + tid;
    int f = idx >> 7, k4 = (idx & 127) << 2;
    float4 v = *(const float4*)(W1 + (size_t)f * 1024 + 512 + k4);
    int ft = f >> 4, col0 = f & 15;
    int kt = k4 >> 5, quad = (k4 >> 3) & 3, e = k4 & 7;
    int F = ft * 16 + kt;
    ushort4 o; o.x = f2b(v.x); o.y = f2b(v.y); o.z = f2b(v.z); o.w = f2b(v.w);
    *(ushort4*)(wQf + ((size_t)F << 9) + ((quad * 16 + col0) << 3) + e) = o;
  } else if (b < 816) {                        // girz[gam*8+a][512]
    int idx = (b - 784) * 256 + tid;
    int c = idx & 511, ga = idx >> 9;
    int a = ga & 7, gam = ga >> 3;
    float s = b_ih[gam * 512 + c] + b_hh[gam * 512 + c];
    if (a < 7) {
      #pragma unroll
      for (int k = 0; k < 4; ++k) s += emb[a * 4 + k] * W_ih[(gam * 512 + c) * 4 + k];
    }
    girz[idx] = s;
  } else if (b < 832) {                        // gin[a][512] = i_n (no b_hh)
    int idx = (b - 816) * 256 + tid;
    int c = idx & 511, a = idx >> 9;
    float s = b_ih[1024 + c];
    if (a < 7) {
      #pragma unroll
      for (int k = 0; k < 4; ++k) s += emb[a * 4 + k] * W_ih[(1024 + c) * 4 + k];
    }
    gin[idx] = s;
  } else if (b < 1088) {                       // projP[s][f] = vision[s] . W1a[f]
    int e = (b - 832) * 256 + tid;
    int s = e >> 5, f = e & 31;
    const float4* vr = (const float4*)(vision + (size_t)s * 512);
    const float4* wr = (const float4*)(W1 + (size_t)f * 1024);
    float a0 = 0.f, a1 = 0.f;
    for (int i = 0; i < 128; i += 2) {
      float4 x = vr[i], w = wr[i];
      float4 y = vr[i + 1], u = wr[i + 1];
      a0 += x.x * w.x + x.y * w.y + x.z * w.z + x.w * w.w;
      a1 += y.x * u.x + y.y * u.y + y.z * u.z + y.w * u.w;
    }
    projP[e] = a0 + a1;
  } else if (b < 1152) {                       // masks: legacy JAX threefry
    int i = (b - 1088) * 256 + tid;
    unsigned a0, b0, a1, b1_;
    tf2x32(0u, 42u, 0u, 2u, a0, b0);
    tf2x32(0u, 42u, 1u, 3u, a1, b1_);
    unsigned p0, p1, n0, n1;
    tf2x32(a0, a1, (unsigned)i, (unsigned)(i + 16384), p0, p1);
    tf2x32(b0, b1_, (unsigned)i, (unsigned)(i + 16384), n0, n1);
    #pragma unroll
    for (int h = 0; h < 2; ++h) {
      int f = i + h * 16384;
      unsigned pw = h ? p1 : p0, nw = h ? n1 : n0;
      int t = f >> 7, j = (f >> 3) & 15, nn = f & 7;
      int ok = (t + j < T_DIM - 1);
      if (ok) {
        int lo = t + 1, hi = t + j + 1, hit = 0;
        #pragma unroll
        for (int q = 0; q < 4; ++q) { int z = env_zeros[nn * 4 + q]; hit |= (z >= lo && z <= hi); }
        ok = !hit;
      }
      unsigned sp = ((pw >> 9) < 0xCCCCDu) ? 1u : 0u;
      unsigned sn = ((nw >> 9) < 0xCCCCDu) ? 2u : 0u;
      maskb[f] = ok ? (unsigned char)(sp | sn) : (unsigned char)0;
    }
  } else if (b == 1152) {                      // zero counters + accum
    if (tid < 4) accum[tid] = 0.f;
    for (int i = tid; i < 2048; i += 256) cnt[i] = 0u;
  } else {                                     // slot0: belief -> A-frag layout
    int i = (b - 1153) * 256 + tid;            // [0, 131072)
    int f = i >> 6, l = i & 63;
    int seq = (f >> 4) * 16 + (l & 15);
    int kb = (f & 15) * 32 + (l >> 4) * 8;
    const float* src = belief + (size_t)seq * 512 + kb;
    float4 v0 = *(const float4*)src, v1 = *(const float4*)(src + 4);
    bf16x8 o;
    o[0] = (short)f2b(v0.x); o[1] = (short)f2b(v0.y); o[2] = (short)f2b(v0.z); o[3] = (short)f2b(v0.w);
    o[4] = (short)f2b(v1.x); o[5] = (short)f2b(v1.y); o[6] = (short)f2b(v1.z); o[7] = (short)f2b(v1.w);
    *(bf16x8*)&hbS[((size_t)f << 9) + l * 8] = o;
  }
}

// ---- persistent GRU ----------------------------------------------------------
__global__ __launch_bounds__(448, 2) void gru_main(
    const float* __restrict__ belief, const int* __restrict__ actions,
    const int* __restrict__ neg_inds,
    const float* __restrict__ b1, const float* __restrict__ W2, const float* __restrict__ b2,
    const float* __restrict__ b_hh,
    const unsigned short* __restrict__ wBf, const unsigned short* __restrict__ wQf,
    const float* __restrict__ girz, const float* __restrict__ gin,
    const float* __restrict__ projP, const unsigned char* __restrict__ maskb,
    unsigned short* __restrict__ hbS, unsigned* __restrict__ cnt,
    float* __restrict__ accum) {
  __shared__ char smem[65536];
  extern __shared__ char occ_blocker[];        // +32KB dynamic -> 96KB: 1 wg/CU
  (void)occ_blocker;
  unsigned short* sA = (unsigned short*)smem;
  float* accL = (float*)smem;                  // alias after GEMM
  unsigned short* bounce = (unsigned short*)(smem + 32768);

  const int tid = threadIdx.x, w = tid >> 6, lane = tid & 63;
  const int b = blockIdx.x;
  const int sl = b >> 5, g = b & 31;
  const int c0 = sl * 64;
  const int seqbase = g * 64;
  const int col0 = lane & 15, quad = lane >> 4;
  const int half = w - 4;

  // B fragments: register-resident for all 16 steps (asm loads can't remat)
  bf16x8 bB[32];
  {
    const unsigned short* p0 = (w < 6)
        ? wBf + ((size_t)((sl * 12 + 2 * w) * 16) << 9) + lane * 8
        : wQf + lane * 8;
    #pragma unroll
    for (int kt = 0; kt < 32; ++kt) bB[kt] = ld_b128(p0 + ((size_t)kt << 9));
    WAITVM0();
  }

  // fp32 h carry in registers (waves 4,5) for all 16 steps
  f32x4 hp[4][2];
  if (w == 4 || w == 5) {
    #pragma unroll
    for (int a = 0; a < 4; ++a)
      #pragma unroll
      for (int t2 = 0; t2 < 2; ++t2) {
        int cc = c0 + half * 32 + t2 * 16 + col0;
        #pragma unroll
        for (int r = 0; r < 4; ++r) {
          int seq = seqbase + 16 * a + quad * 4 + r;
          hp[a][t2][r] = belief[(size_t)seq * 512 + cc];
        }
      }
  }

  const bool isCls = (w == 6) && (sl == 0);
  float b1v0 = 0.f, b1v1 = 0.f, w2v0 = 0.f, w2v1 = 0.f, b2v = 0.f;
  if (isCls) { b1v0 = b1[col0]; b1v1 = b1[col0 + 16];
               w2v0 = W2[col0]; w2v1 = W2[col0 + 16]; b2v = b2[0]; }
  float sumP = 0.f, cntP = 0.f, sumN = 0.f, cntN = 0.f;

  for (int j = 0; j <= KK; ++j) {
    // ---- group barrier: all 8 slices arrived at step j-1 ----
    if (j > 0) {
      if (tid == 0) {
        const unsigned tgt = 8u * (unsigned)j;
        while (ld_u32_bypass(cnt + g * 64) < tgt) __builtin_amdgcn_s_sleep(1);
      }
      __syncthreads();
    }
    // ---- stage h_j from S[j%3] (L3-direct), statically batched ----
    {
      const unsigned short* src = hbS + (size_t)(j % 3) * 1048576 + ((size_t)(g * 64) << 9);
#define SRCAT(I) (src + (((I) >> 6) << 9) + (((I) & 63) << 3))
#define SAAT(I)  ((bf16x8*)&sA[(((I) >> 6) << 9) + (((I) & 63) << 3)])
      bf16x8 tA0 = ld_b128_bypass(SRCAT(tid));
      bf16x8 tA1 = ld_b128_bypass(SRCAT(tid + 448));
      bf16x8 tA2 = ld_b128_bypass(SRCAT(tid + 896));
      bf16x8 tA3 = ld_b128_bypass(SRCAT(tid + 1344));
      bf16x8 tA4 = ld_b128_bypass(SRCAT(tid + 1792));
      WAITVM0();
      *SAAT(tid) = tA0; *SAAT(tid + 448) = tA1; *SAAT(tid + 896) = tA2;
      *SAAT(tid + 1344) = tA3; *SAAT(tid + 1792) = tA4;
      tA0 = ld_b128_bypass(SRCAT(tid + 2240));
      tA1 = ld_b128_bypass(SRCAT(tid + 2688));
      tA2 = ld_b128_bypass(SRCAT(tid + 3136));
      tA3 = ld_b128_bypass(SRCAT(tid + 3584));
      const bool ten = (tid < 64);
      if (ten) tA4 = ld_b128_bypass(SRCAT(tid + 4032));
      WAITVM0();
      *SAAT(tid + 2240) = tA0; *SAAT(tid + 2688) = tA1;
      *SAAT(tid + 3136) = tA2; *SAAT(tid + 3584) = tA3;
      if (ten) *SAAT(tid + 4032) = tA4;
#undef SRCAT
#undef SAAT
    }
    __syncthreads();

    // ---- GEMM ----
    f32x4 acc[4][2];
    #pragma unroll
    for (int a = 0; a < 4; ++a) { acc[a][0] = (f32x4){0,0,0,0}; acc[a][1] = (f32x4){0,0,0,0}; }
    const bool doGates = (w < 6) && (j < KK);
    const bool doCls = isCls && (j > 0);
    if (doGates || doCls) {
      #pragma unroll
      for (int kt = 0; kt < 16; ++kt) {
        #pragma unroll
        for (int a = 0; a < 4; ++a) {
          bf16x8 af = *(const bf16x8*)&sA[((a * 16 + kt) << 9) + (lane << 3)];
          acc[a][0] = MFMA16(af, bB[kt], acc[a][0]);
          acc[a][1] = MFMA16(af, bB[16 + kt], acc[a][1]);
        }
      }
    }
    __syncthreads();   // sA dead; accL/bounce alias live

    if (doCls) {                               // classifier + loss for jq = j-1
      const int jq = j - 1;
      float wj = (jq == 0) ? 5.f : (jq == 1) ? 4.f : (jq < 4) ? 3.f : (jq < 8) ? 2.f : 1.f;
      #pragma unroll
      for (int a = 0; a < 4; ++a)
        #pragma unroll
        for (int r = 0; r < 4; ++r) {
          int seq = seqbase + 16 * a + quad * 4 + r;
          int t = seq >> 3, nn = seq & 7;
          unsigned mb = maskb[(t << 7) + (jq << 3) + nn];
          float pp0 = 0.f, pp1 = 0.f, pn0 = 0.f, pn1 = 0.f;
          if (mb) {
            int sp = seq + j * 8;
            pp0 = projP[(sp << 5) + col0];  pp1 = projP[(sp << 5) + 16 + col0];
            int ni = neg_inds[sp];
            pn0 = projP[(ni << 5) + col0];  pn1 = projP[(ni << 5) + 16 + col0];
          }
          float a0v = acc[a][0][r] + b1v0, a1v = acc[a][1][r] + b1v1;
          float pl = fmaxf(a0v + pp0, 0.f) * w2v0 + fmaxf(a1v + pp1, 0.f) * w2v1;
          float nl = fmaxf(a0v + pn0, 0.f) * w2v0 + fmaxf(a1v + pn1, 0.f) * w2v1;
          #pragma unroll
          for (int d = 1; d < 16; d <<= 1) {
            pl += __shfl_xor(pl, d, 64);
            nl += __shfl_xor(nl, d, 64);
          }
          if (col0 == 0 && mb) {
            if (mb & 1u) {
              float x = -(pl + b2v);
              sumP += wj * (fmaxf(x, 0.f) + __logf(1.f + __expf(-fabsf(x))));
              cntP += 1.f;
            }
            if (mb & 2u) {
              float x = (nl + b2v);
              sumN += wj * (fmaxf(x, 0.f) + __logf(1.f + __expf(-fabsf(x))));
              cntN += 1.f;
            }
          }
        }
    }

    if (j < KK) {
      // phase B: r,z waves publish accs
      if (w < 4) {
        #pragma unroll
        for (int t2 = 0; t2 < 2; ++t2)
          #pragma unroll
          for (int a = 0; a < 4; ++a) {
            int nu = 2 * w + t2;
            *(f32x4*)&accL[((nu * 4 + a) * 64 + lane) * 4] = acc[a][t2];
          }
      }
      __syncthreads();
      // phase C: n-gate waves do the GRU epilogue
      if (w == 4 || w == 5) {
        #pragma unroll
        for (int t2 = 0; t2 < 2; ++t2) {
          int q = half * 2 + t2;
          int cc = c0 + half * 32 + t2 * 16 + col0;
          float bhhn = b_hh[1024 + cc];
          #pragma unroll
          for (int a = 0; a < 4; ++a) {
            f32x4 aR = *(const f32x4*)&accL[((q * 4 + a) * 64 + lane) * 4];
            f32x4 aZ = *(const f32x4*)&accL[(((4 + q) * 4 + a) * 64 + lane) * 4];
            #pragma unroll
            for (int r = 0; r < 4; ++r) {
              int row = quad * 4 + r;
              int seq = seqbase + 16 * a + row;
              int t = seq >> 3, nn = seq & 7, tj = t + j;
              int ai = (tj < T_DIM) ? actions[tj * 8 + nn] : 7;
              float rg = 1.f / (1.f + __expf(-(aR[r] + girz[(ai << 9) + cc])));
              float zg = 1.f / (1.f + __expf(-(aZ[r] + girz[((8 + ai) << 9) + cc])));
              float pre = gin[(ai << 9) + cc] + rg * (acc[a][t2][r] + bhhn);
              float cand = 1.f - 2.f / (1.f + __expf(2.f * pre));
              float hn = (1.f - zg) * cand + zg * hp[a][t2][r];
              hp[a][t2][r] = hn;
              bounce[(16 * a + row) * 72 + half * 32 + t2 * 16 + col0] = f2b(hn);
            }
          }
        }
      }
      __syncthreads();
      // phase D: publish our slice's h_{j+1} frags to S[(j+1)%3] (L3-direct)
      unsigned short* dst = hbS + (size_t)((j + 1) % 3) * 1048576;
      {
        int f = tid >> 6, l = tid & 63;
        int a = f >> 1, ktl = f & 1;
        bf16x8 v = *(const bf16x8*)&bounce[(16 * a + (l & 15)) * 72 + 32 * ktl + (l >> 4) * 8];
        st_b128_bypass(&dst[((size_t)(g * 64 + a * 16 + sl * 2 + ktl) << 9) + (l << 3)], v);
        if (tid < 64) {
          int i2 = tid + 448;
          int f2 = i2 >> 6, l2 = i2 & 63;
          int a2 = f2 >> 1, ktl2 = f2 & 1;
          bf16x8 v2 = *(const bf16x8*)&bounce[(16 * a2 + (l2 & 15)) * 72 + 32 * ktl2 + (l2 >> 4) * 8];
          st_b128_bypass(&dst[((size_t)(g * 64 + a2 * 16 + sl * 2 + ktl2) << 9) + (l2 << 3)], v2);
        }
      }
      WAITVM0();
      __syncthreads();                         // all threads' stores at L3
      if (tid == 0) atomicAdd(cnt + g * 64, 1u);   // arrive (device-scope, at L3)
    }
  }

  if (isCls && col0 == 0) {
    atomicAdd(&accum[0], sumP); atomicAdd(&accum[1], cntP);
    atomicAdd(&accum[2], sumN); atomicAdd(&accum[3], cntN);
  }
}

__global__ void fin(const float* __restrict__ accum, float* __restrict__ out) {
  out[0] = (accum[0] / fmaxf(accum[1], 1.f) + accum[2] / fmaxf(accum[3], 1.f)) * 0.1f;
}

extern "C" void kernel_launch(void* const* d_in, const int* in_sizes, int n_in,
                              void* d_out, int out_size, void* d_ws, size_t ws_size,
                              hipStream_t stream) {
  const float* vision  = (const float*)d_in[0];
  const float* belief  = (const float*)d_in[1];
  const int*   actions = (const int*)d_in[2];
  const int*   envz    = (const int*)d_in[3];
  const int*   negi    = (const int*)d_in[4];
  const float* emb     = (const float*)d_in[5];
  const float* W_ih    = (const float*)d_in[6];
  const float* W_hh    = (const float*)d_in[7];
  const float* b_ih    = (const float*)d_in[8];
  const float* b_hh    = (const float*)d_in[9];
  const float* W1      = (const float*)d_in[10];
  const float* b1      = (const float*)d_in[11];
  const float* W2      = (const float*)d_in[12];
  const float* b2      = (const float*)d_in[13];

  char* ws = (char*)d_ws;
  float*          accum = (float*)(ws + 0);
  unsigned*       cnt   = (unsigned*)(ws + 256);             // 32 x 64 ints (padded)
  unsigned short* wBf   = (unsigned short*)(ws + 8704);      // 1572864 B
  unsigned short* wQf   = (unsigned short*)(ws + 1581568);   // 32768 B
  float*          girz  = (float*)(ws + 1614336);            // 32768 B
  float*          gin   = (float*)(ws + 1647104);            // 16384 B
  float*          projP = (float*)(ws + 1663488);            // 262144 B
  unsigned char*  maskb = (unsigned char*)(ws + 1925632);    // 32768 B
  unsigned short* hbS   = (unsigned short*)(ws + 1958912);   // 3 x 2097152 B

  prep<<<1665, 256, 0, stream>>>(W_hh, W1, emb, W_ih, b_ih, b_hh, vision, envz,
                                 belief, wBf, wQf, girz, gin, projP, maskb,
                                 hbS, cnt, accum);
  gru_main<<<256, 448, 32768, stream>>>(belief, actions, negi, b1, W2, b2, b_hh,
                                        wBf, wQf, girz, gin, projP, maskb,
                                        hbS, cnt, accum);
  fin<<<1, 1, 0, stream>>>(accum, (float*)d_out);
}

// Round 6
// 375.096 us; speedup vs baseline: 4.0130x; 1.3923x over previous
//
#include <hip/hip_runtime.h>
#include <hip/hip_bf16.h>

// CPCA_Weighted: T=256 N=8 H=512 K=16 A=4, 7 actions, P_SUB=0.1, LOSS_FACTOR=0.1
// R6: persistent GRU, 256 wgs x 384 thr (6 uniform waves), B reg-resident
// (fits 256-VGPR cap now), 17 h-slots (no rotation), cls as separate kernel.
#define T_DIM 256
#define KK    16

typedef __attribute__((ext_vector_type(8))) short bf16x8;
typedef __attribute__((ext_vector_type(4))) float f32x4;

#define MFMA16(A, B, C) __builtin_amdgcn_mfma_f32_16x16x32_bf16(A, B, C, 0, 0, 0)
#define SLOT 1048576   // shorts per h slot (2048 seqs x 512)

__device__ __forceinline__ unsigned short f2b(float x) {
  unsigned u = __float_as_uint(x);
  unsigned r = (u + 0x7FFFu + ((u >> 16) & 1u)) >> 16;   // RNE
  return (unsigned short)r;
}

// ---- L3-coherent ops for cross-wg communication (verified in R5) -------------
__device__ __forceinline__ bf16x8 ld_b128_bypass(const unsigned short* p) {
  bf16x8 r;
  asm volatile("global_load_dwordx4 %0, %1, off sc0 sc1" : "=v"(r) : "v"(p) : "memory");
  return r;
}
__device__ __forceinline__ void st_b128_bypass(unsigned short* p, bf16x8 v) {
  asm volatile("global_store_dwordx4 %0, %1, off sc0 sc1" :: "v"(p), "v"(v) : "memory");
}
__device__ __forceinline__ unsigned ld_u32_bypass(const unsigned* p) {
  unsigned r;
  asm volatile("global_load_dword %0, %1, off sc0 sc1\n\ts_waitcnt vmcnt(0)"
               : "=v"(r) : "v"(p) : "memory");
  return r;
}
__device__ __forceinline__ bf16x8 ld_b128(const unsigned short* p) {
  bf16x8 r;
  asm volatile("global_load_dwordx4 %0, %1, off" : "=v"(r) : "v"(p) : "memory");
  return r;
}
#define WAITVM0() asm volatile("s_waitcnt vmcnt(0)" ::: "memory")

// JAX threefry2x32 (20 rounds)
__device__ __forceinline__ void tf2x32(unsigned k0, unsigned k1, unsigned x0, unsigned x1,
                                       unsigned &o0, unsigned &o1) {
  unsigned ks2 = k0 ^ k1 ^ 0x1BD11BDAu;
  x0 += k0; x1 += k1;
#define TFR(R) { x0 += x1; x1 = (x1 << R) | (x1 >> (32 - R)); x1 ^= x0; }
  TFR(13) TFR(15) TFR(26) TFR(6)   x0 += k1;  x1 += ks2 + 1u;
  TFR(17) TFR(29) TFR(16) TFR(24)  x0 += ks2; x1 += k0 + 2u;
  TFR(13) TFR(15) TFR(26) TFR(6)   x0 += k0;  x1 += k1 + 3u;
  TFR(17) TFR(29) TFR(16) TFR(24)  x0 += k1;  x1 += ks2 + 4u;
  TFR(13) TFR(15) TFR(26) TFR(6)   x0 += ks2; x1 += k0 + 5u;
#undef TFR
  o0 = x0; o1 = x1;
}

// ---- prep: coalesced-read swizzles, tables, masks, slot0, zeros --------------
__global__ void prep(const float* __restrict__ W_hh, const float* __restrict__ W1,
                     const float* __restrict__ emb,  const float* __restrict__ W_ih,
                     const float* __restrict__ b_ih, const float* __restrict__ b_hh,
                     const float* __restrict__ vision, const int* __restrict__ env_zeros,
                     const float* __restrict__ belief,
                     unsigned short* __restrict__ wBf, unsigned short* __restrict__ wQf,
                     float* __restrict__ girz, float* __restrict__ gin,
                     float* __restrict__ projP, unsigned char* __restrict__ maskb,
                     unsigned short* __restrict__ hbS, unsigned* __restrict__ cnt,
                     float* __restrict__ accum) {
  int b = blockIdx.x, tid = threadIdx.x;
  if (b < 768) {                               // wBf swizzle: coalesced read W_hh
    int idx = b * 256 + tid;
    int row = idx >> 7, k4 = (idx & 127) << 2;
    float4 v = *(const float4*)(W_hh + ((size_t)row << 9) + k4);
    int gam = row >> 9, sl = (row >> 6) & 7, q = (row >> 4) & 3, col0 = row & 15;
    int kt = k4 >> 5, quad = (k4 >> 3) & 3, e = k4 & 7;
    int F = (sl * 12 + gam * 4 + q) * 16 + kt;
    ushort4 o; o.x = f2b(v.x); o.y = f2b(v.y); o.z = f2b(v.z); o.w = f2b(v.w);
    *(ushort4*)(wBf + ((size_t)F << 9) + ((quad * 16 + col0) << 3) + e) = o;
  } else if (b < 784) {                        // wQf swizzle
    int idx = (b - 768) * 256 + tid;
    int f = idx >> 7, k4 = (idx & 127) << 2;
    float4 v = *(const float4*)(W1 + (size_t)f * 1024 + 512 + k4);
    int ft = f >> 4, col0 = f & 15;
    int kt = k4 >> 5, quad = (k4 >> 3) & 3, e = k4 & 7;
    int F = ft * 16 + kt;
    ushort4 o; o.x = f2b(v.x); o.y = f2b(v.y); o.z = f2b(v.z); o.w = f2b(v.w);
    *(ushort4*)(wQf + ((size_t)F << 9) + ((quad * 16 + col0) << 3) + e) = o;
  } else if (b < 816) {                        // girz[gam*8+a][512]
    int idx = (b - 784) * 256 + tid;
    int c = idx & 511, ga = idx >> 9;
    int a = ga & 7, gam = ga >> 3;
    float s = b_ih[gam * 512 + c] + b_hh[gam * 512 + c];
    if (a < 7) {
      #pragma unroll
      for (int k = 0; k < 4; ++k) s += emb[a * 4 + k] * W_ih[(gam * 512 + c) * 4 + k];
    }
    girz[idx] = s;
  } else if (b < 832) {                        // gin[a][512] = i_n (no b_hh)
    int idx = (b - 816) * 256 + tid;
    int c = idx & 511, a = idx >> 9;
    float s = b_ih[1024 + c];
    if (a < 7) {
      #pragma unroll
      for (int k = 0; k < 4; ++k) s += emb[a * 4 + k] * W_ih[(1024 + c) * 4 + k];
    }
    gin[idx] = s;
  } else if (b < 1088) {                       // projP[s][f] = vision[s] . W1a[f]
    int e = (b - 832) * 256 + tid;
    int s = e >> 5, f = e & 31;
    const float4* vr = (const float4*)(vision + (size_t)s * 512);
    const float4* wr = (const float4*)(W1 + (size_t)f * 1024);
    float a0 = 0.f, a1 = 0.f;
    for (int i = 0; i < 128; i += 2) {
      float4 x = vr[i], w = wr[i];
      float4 y = vr[i + 1], u = wr[i + 1];
      a0 += x.x * w.x + x.y * w.y + x.z * w.z + x.w * w.w;
      a1 += y.x * u.x + y.y * u.y + y.z * u.z + y.w * u.w;
    }
    projP[e] = a0 + a1;
  } else if (b < 1152) {                       // masks: legacy JAX threefry
    int i = (b - 1088) * 256 + tid;
    unsigned a0, b0, a1, b1_;
    tf2x32(0u, 42u, 0u, 2u, a0, b0);
    tf2x32(0u, 42u, 1u, 3u, a1, b1_);
    unsigned p0, p1, n0, n1;
    tf2x32(a0, a1, (unsigned)i, (unsigned)(i + 16384), p0, p1);
    tf2x32(b0, b1_, (unsigned)i, (unsigned)(i + 16384), n0, n1);
    #pragma unroll
    for (int h = 0; h < 2; ++h) {
      int f = i + h * 16384;
      unsigned pw = h ? p1 : p0, nw = h ? n1 : n0;
      int t = f >> 7, j = (f >> 3) & 15, nn = f & 7;
      int ok = (t + j < T_DIM - 1);
      if (ok) {
        int lo = t + 1, hi = t + j + 1, hit = 0;
        #pragma unroll
        for (int q = 0; q < 4; ++q) { int z = env_zeros[nn * 4 + q]; hit |= (z >= lo && z <= hi); }
        ok = !hit;
      }
      unsigned sp = ((pw >> 9) < 0xCCCCDu) ? 1u : 0u;
      unsigned sn = ((nw >> 9) < 0xCCCCDu) ? 2u : 0u;
      maskb[f] = ok ? (unsigned char)(sp | sn) : (unsigned char)0;
    }
  } else if (b == 1152) {                      // zero counters + accum
    if (tid < 4) accum[tid] = 0.f;
    for (int i = tid; i < 2048; i += 256) cnt[i] = 0u;
  } else {                                     // slot0: belief -> A-frag layout
    int i = (b - 1153) * 256 + tid;            // [0, 131072)
    int f = i >> 6, l = i & 63;
    int seq = (f >> 4) * 16 + (l & 15);
    int kb = (f & 15) * 32 + (l >> 4) * 8;
    const float* src = belief + (size_t)seq * 512 + kb;
    float4 v0 = *(const float4*)src, v1 = *(const float4*)(src + 4);
    bf16x8 o;
    o[0] = (short)f2b(v0.x); o[1] = (short)f2b(v0.y); o[2] = (short)f2b(v0.z); o[3] = (short)f2b(v0.w);
    o[4] = (short)f2b(v1.x); o[5] = (short)f2b(v1.y); o[6] = (short)f2b(v1.z); o[7] = (short)f2b(v1.w);
    *(bf16x8*)&hbS[((size_t)f << 9) + l * 8] = o;
  }
}

// ---- persistent GRU: 6 uniform waves, B in registers -------------------------
__global__ __launch_bounds__(384, 2) void gru_main(
    const float* __restrict__ belief, const int* __restrict__ actions,
    const float* __restrict__ b_hh,
    const unsigned short* __restrict__ wBf,
    const float* __restrict__ girz, const float* __restrict__ gin,
    unsigned short* __restrict__ hbS, unsigned* __restrict__ cnt) {
  __shared__ char smem[65536];
  extern __shared__ char occ_blocker[];        // +48KB dynamic: 1 wg/CU by LDS
  (void)occ_blocker;
  unsigned short* sA = (unsigned short*)smem;          // 64 frags x 1KB
  float* accL = (float*)smem;                          // alias after GEMM (32KB)
  unsigned short* bounce = (unsigned short*)(smem + 32768);  // [64][72]

  const int tid = threadIdx.x, w = tid >> 6, lane = tid & 63;
  const int b = blockIdx.x;
  const int sl = b >> 5, g = b & 31;           // slices of a group share an XCD
  const int c0 = sl * 64;
  const int seqbase = g * 64;
  const int col0 = lane & 15, quad = lane >> 4;
  const int half = w - 4;

  // B fragments: 2 N-tiles per wave, register-resident for all 16 steps
  bf16x8 bB[32];
  {
    const unsigned short* p0 = wBf + ((size_t)((sl * 12 + 2 * w) * 16) << 9) + lane * 8;
    #pragma unroll
    for (int kt = 0; kt < 32; ++kt) bB[kt] = ld_b128(p0 + ((size_t)kt << 9));
    WAITVM0();
  }

  // fp32 h carry in registers (waves 4,5 = n-gate owners)
  f32x4 hp[4][2];
  if (w >= 4) {
    #pragma unroll
    for (int a = 0; a < 4; ++a)
      #pragma unroll
      for (int t2 = 0; t2 < 2; ++t2) {
        int cc = c0 + half * 32 + t2 * 16 + col0;
        #pragma unroll
        for (int r = 0; r < 4; ++r) {
          int seq = seqbase + 16 * a + quad * 4 + r;
          hp[a][t2][r] = belief[(size_t)seq * 512 + cc];
        }
      }
  }

  for (int j = 0; j < KK; ++j) {
    // ---- group barrier: all 8 slices published h_j ----
    if (j > 0) {
      if (tid == 0) {
        const unsigned tgt = 8u * (unsigned)j;
        while (ld_u32_bypass(cnt + g * 64) < tgt) __builtin_amdgcn_s_sleep(1);
      }
      __syncthreads();
    }
    // ---- stage h_j from slot j (linear frag copy, batched loads) ----
    {
      const unsigned short* src = hbS + (size_t)j * SLOT + ((size_t)(g * 64) << 9);
      bf16x8 t0 = ld_b128_bypass(src + ((size_t)(tid)        << 3));
      bf16x8 t1 = ld_b128_bypass(src + ((size_t)(tid + 384)  << 3));
      bf16x8 t2 = ld_b128_bypass(src + ((size_t)(tid + 768)  << 3));
      bf16x8 t3 = ld_b128_bypass(src + ((size_t)(tid + 1152) << 3));
      bf16x8 t4 = ld_b128_bypass(src + ((size_t)(tid + 1536) << 3));
      bf16x8 t5 = ld_b128_bypass(src + ((size_t)(tid + 1920) << 3));
      bf16x8 t6 = ld_b128_bypass(src + ((size_t)(tid + 2304) << 3));
      bf16x8 t7 = ld_b128_bypass(src + ((size_t)(tid + 2688) << 3));
      bf16x8 t8 = ld_b128_bypass(src + ((size_t)(tid + 3072) << 3));
      bf16x8 t9 = ld_b128_bypass(src + ((size_t)(tid + 3456) << 3));
      bf16x8 tA; const bool ex = (tid < 256);
      if (ex) tA = ld_b128_bypass(src + ((size_t)(tid + 3840) << 3));
      WAITVM0();
      *(bf16x8*)&sA[(size_t)(tid)        << 3] = t0;
      *(bf16x8*)&sA[(size_t)(tid + 384)  << 3] = t1;
      *(bf16x8*)&sA[(size_t)(tid + 768)  << 3] = t2;
      *(bf16x8*)&sA[(size_t)(tid + 1152) << 3] = t3;
      *(bf16x8*)&sA[(size_t)(tid + 1536) << 3] = t4;
      *(bf16x8*)&sA[(size_t)(tid + 1920) << 3] = t5;
      *(bf16x8*)&sA[(size_t)(tid + 2304) << 3] = t6;
      *(bf16x8*)&sA[(size_t)(tid + 2688) << 3] = t7;
      *(bf16x8*)&sA[(size_t)(tid + 3072) << 3] = t8;
      *(bf16x8*)&sA[(size_t)(tid + 3456) << 3] = t9;
      if (ex) *(bf16x8*)&sA[(size_t)(tid + 3840) << 3] = tA;
    }
    __syncthreads();

    // ---- GEMM: all 6 waves, 128 MFMA each ----
    f32x4 acc[4][2];
    #pragma unroll
    for (int a = 0; a < 4; ++a) { acc[a][0] = (f32x4){0,0,0,0}; acc[a][1] = (f32x4){0,0,0,0}; }
    #pragma unroll
    for (int kt = 0; kt < 16; ++kt) {
      #pragma unroll
      for (int a = 0; a < 4; ++a) {
        bf16x8 af = *(const bf16x8*)&sA[((a * 16 + kt) << 9) + (lane << 3)];
        acc[a][0] = MFMA16(af, bB[kt], acc[a][0]);
        acc[a][1] = MFMA16(af, bB[16 + kt], acc[a][1]);
      }
    }
    __syncthreads();   // sA dead; accL/bounce alias live

    // ---- r,z waves publish accs ----
    if (w < 4) {
      #pragma unroll
      for (int t2 = 0; t2 < 2; ++t2)
        #pragma unroll
        for (int a = 0; a < 4; ++a) {
          int nu = 2 * w + t2;
          *(f32x4*)&accL[((nu * 4 + a) * 64 + lane) * 4] = acc[a][t2];
        }
    }
    __syncthreads();

    // ---- n-gate waves: GRU epilogue for their 32-col half ----
    if (w >= 4) {
      #pragma unroll
      for (int t2 = 0; t2 < 2; ++t2) {
        int q = half * 2 + t2;
        int cc = c0 + half * 32 + t2 * 16 + col0;
        float bhhn = b_hh[1024 + cc];
        #pragma unroll
        for (int a = 0; a < 4; ++a) {
          f32x4 aR = *(const f32x4*)&accL[((q * 4 + a) * 64 + lane) * 4];
          f32x4 aZ = *(const f32x4*)&accL[(((4 + q) * 4 + a) * 64 + lane) * 4];
          #pragma unroll
          for (int r = 0; r < 4; ++r) {
            int row = quad * 4 + r;
            int seq = seqbase + 16 * a + row;
            int t = seq >> 3, nn = seq & 7, tj = t + j;
            int ai = (tj < T_DIM) ? actions[tj * 8 + nn] : 7;
            float rg = 1.f / (1.f + __expf(-(aR[r] + girz[(ai << 9) + cc])));
            float zg = 1.f / (1.f + __expf(-(aZ[r] + girz[((8 + ai) << 9) + cc])));
            float pre = gin[(ai << 9) + cc] + rg * (acc[a][t2][r] + bhhn);
            float cand = 1.f - 2.f / (1.f + __expf(2.f * pre));
            float hn = (1.f - zg) * cand + zg * hp[a][t2][r];
            hp[a][t2][r] = hn;
            bounce[(16 * a + row) * 72 + half * 32 + t2 * 16 + col0] = f2b(hn);
          }
        }
      }
    }
    __syncthreads();

    // ---- publish our slice's h_{j+1} frags to slot j+1 (write-through) ----
    unsigned short* dst = hbS + (size_t)(j + 1) * SLOT;
    {
      int f = tid >> 6, l = tid & 63;
      int a = f >> 1, ktl = f & 1;
      bf16x8 v = *(const bf16x8*)&bounce[(16 * a + (l & 15)) * 72 + 32 * ktl + (l >> 4) * 8];
      st_b128_bypass(&dst[((size_t)(g * 64 + a * 16 + sl * 2 + ktl) << 9) + (l << 3)], v);
      if (tid < 128) {
        int i2 = tid + 384;
        int f2 = i2 >> 6, l2 = i2 & 63;
        int a2 = f2 >> 1, ktl2 = f2 & 1;
        bf16x8 v2 = *(const bf16x8*)&bounce[(16 * a2 + (l2 & 15)) * 72 + 32 * ktl2 + (l2 >> 4) * 8];
        st_b128_bypass(&dst[((size_t)(g * 64 + a2 * 16 + sl * 2 + ktl2) << 9) + (l2 << 3)], v2);
      }
    }
    WAITVM0();                                 // each thread drains its own stores
    __syncthreads();                           // => all wg stores at L3
    if (tid == 0) atomicAdd(cnt + g * 64, 1u);
  }
}

// ---- classifier + loss over all 16 offsets (reads retained h slots) ----------
__global__ __launch_bounds__(64, 1) void cls(
    const unsigned short* __restrict__ hbS, const unsigned short* __restrict__ wQf,
    const int* __restrict__ neg_inds,
    const float* __restrict__ b1, const float* __restrict__ W2, const float* __restrict__ b2,
    const float* __restrict__ projP, const unsigned char* __restrict__ maskb,
    float* __restrict__ accum) {
  const int g = blockIdx.x >> 4, jq = blockIdx.x & 15;
  const int lane = threadIdx.x;
  const int col0 = lane & 15, quad = lane >> 4;
  const int seqbase = g * 64;
  const int j = jq + 1;

  const unsigned short* hsrc = hbS + (size_t)j * SLOT + ((size_t)(g * 64) << 9);
  f32x4 acc[4][2];
  #pragma unroll
  for (int a = 0; a < 4; ++a) { acc[a][0] = (f32x4){0,0,0,0}; acc[a][1] = (f32x4){0,0,0,0}; }
  const unsigned short* qp = wQf + lane * 8;
  for (int kt = 0; kt < 16; ++kt) {
    bf16x8 bq0 = *(const bf16x8*)(qp + ((size_t)kt << 9));
    bf16x8 bq1 = *(const bf16x8*)(qp + ((size_t)(16 + kt) << 9));
    #pragma unroll
    for (int a = 0; a < 4; ++a) {
      bf16x8 af = *(const bf16x8*)&hsrc[((size_t)(a * 16 + kt) << 9) + lane * 8];
      acc[a][0] = MFMA16(af, bq0, acc[a][0]);
      acc[a][1] = MFMA16(af, bq1, acc[a][1]);
    }
  }
  float b1v0 = b1[col0], b1v1 = b1[col0 + 16];
  float w2v0 = W2[col0], w2v1 = W2[col0 + 16], b2v = b2[0];
  float wj = (jq == 0) ? 5.f : (jq == 1) ? 4.f : (jq < 4) ? 3.f : (jq < 8) ? 2.f : 1.f;
  float sumP = 0.f, cntP = 0.f, sumN = 0.f, cntN = 0.f;
  #pragma unroll
  for (int a = 0; a < 4; ++a)
    #pragma unroll
    for (int r = 0; r < 4; ++r) {
      int seq = seqbase + 16 * a + quad * 4 + r;
      int t = seq >> 3, nn = seq & 7;
      unsigned mb = maskb[(t << 7) + (jq << 3) + nn];
      float pp0 = 0.f, pp1 = 0.f, pn0 = 0.f, pn1 = 0.f;
      if (mb) {
        int sp = seq + j * 8;
        pp0 = projP[(sp << 5) + col0];  pp1 = projP[(sp << 5) + 16 + col0];
        int ni = neg_inds[sp];
        pn0 = projP[(ni << 5) + col0];  pn1 = projP[(ni << 5) + 16 + col0];
      }
      float a0v = acc[a][0][r] + b1v0, a1v = acc[a][1][r] + b1v1;
      float pl = fmaxf(a0v + pp0, 0.f) * w2v0 + fmaxf(a1v + pp1, 0.f) * w2v1;
      float nl = fmaxf(a0v + pn0, 0.f) * w2v0 + fmaxf(a1v + pn1, 0.f) * w2v1;
      #pragma unroll
      for (int d = 1; d < 16; d <<= 1) {
        pl += __shfl_xor(pl, d, 64);
        nl += __shfl_xor(nl, d, 64);
      }
      if (col0 == 0 && mb) {
        if (mb & 1u) {
          float x = -(pl + b2v);
          sumP += wj * (fmaxf(x, 0.f) + __logf(1.f + __expf(-fabsf(x))));
          cntP += 1.f;
        }
        if (mb & 2u) {
          float x = (nl + b2v);
          sumN += wj * (fmaxf(x, 0.f) + __logf(1.f + __expf(-fabsf(x))));
          cntN += 1.f;
        }
      }
    }
  if (col0 == 0) {
    atomicAdd(&accum[0], sumP); atomicAdd(&accum[1], cntP);
    atomicAdd(&accum[2], sumN); atomicAdd(&accum[3], cntN);
  }
}

__global__ void fin(const float* __restrict__ accum, float* __restrict__ out) {
  out[0] = (accum[0] / fmaxf(accum[1], 1.f) + accum[2] / fmaxf(accum[3], 1.f)) * 0.1f;
}

extern "C" void kernel_launch(void* const* d_in, const int* in_sizes, int n_in,
                              void* d_out, int out_size, void* d_ws, size_t ws_size,
                              hipStream_t stream) {
  const float* vision  = (const float*)d_in[0];
  const float* belief  = (const float*)d_in[1];
  const int*   actions = (const int*)d_in[2];
  const int*   envz    = (const int*)d_in[3];
  const int*   negi    = (const int*)d_in[4];
  const float* emb     = (const float*)d_in[5];
  const float* W_ih    = (const float*)d_in[6];
  const float* W_hh    = (const float*)d_in[7];
  const float* b_ih    = (const float*)d_in[8];
  const float* b_hh    = (const float*)d_in[9];
  const float* W1      = (const float*)d_in[10];
  const float* b1      = (const float*)d_in[11];
  const float* W2      = (const float*)d_in[12];
  const float* b2      = (const float*)d_in[13];

  char* ws = (char*)d_ws;
  float*          accum = (float*)(ws + 0);
  unsigned*       cnt   = (unsigned*)(ws + 256);             // 32 groups x 64 ints
  unsigned short* wBf   = (unsigned short*)(ws + 8704);      // 1572864 B
  unsigned short* wQf   = (unsigned short*)(ws + 1581568);   // 32768 B
  float*          girz  = (float*)(ws + 1614336);            // 32768 B
  float*          gin   = (float*)(ws + 1647104);            // 16384 B
  float*          projP = (float*)(ws + 1663488);            // 262144 B
  unsigned char*  maskb = (unsigned char*)(ws + 1925632);    // 32768 B
  unsigned short* hbS   = (unsigned short*)(ws + 1958912);   // 17 x 2097152 B

  prep<<<1665, 256, 0, stream>>>(W_hh, W1, emb, W_ih, b_ih, b_hh, vision, envz,
                                 belief, wBf, wQf, girz, gin, projP, maskb,
                                 hbS, cnt, accum);
  gru_main<<<256, 384, 49152, stream>>>(belief, actions, b_hh, wBf, girz, gin,
                                        hbS, cnt);
  cls<<<512, 64, 0, stream>>>(hbS, wQf, negi, b1, W2, b2, projP, maskb, accum);
  fin<<<1, 1, 0, stream>>>(accum, (float*)d_out);
}

// Round 7
// 279.495 us; speedup vs baseline: 5.3856x; 1.3420x over previous
//
#include <hip/hip_runtime.h>
#include <hip/hip_bf16.h>

// CPCA_Weighted: T=256 N=8 H=512 K=16 A=4, 7 actions, P_SUB=0.1, LOSS_FACTOR=0.1
// R7: R6 core (persistent 256x384, B reg-resident, L3 exchange + group barrier)
// + balanced 6-wave epilogue (hp in LDS), sl-rotated stage, atomic-free cls.
#define T_DIM 256
#define KK    16

typedef __attribute__((ext_vector_type(8))) short bf16x8;
typedef __attribute__((ext_vector_type(4))) float f32x4;

#define MFMA16(A, B, C) __builtin_amdgcn_mfma_f32_16x16x32_bf16(A, B, C, 0, 0, 0)
#define SLOT 1048576   // shorts per h slot (2048 seqs x 512)

__device__ __forceinline__ unsigned short f2b(float x) {
  unsigned u = __float_as_uint(x);
  unsigned r = (u + 0x7FFFu + ((u >> 16) & 1u)) >> 16;   // RNE
  return (unsigned short)r;
}

// ---- L3-coherent ops for cross-wg communication (verified R5/R6) -------------
__device__ __forceinline__ bf16x8 ld_b128_bypass(const unsigned short* p) {
  bf16x8 r;
  asm volatile("global_load_dwordx4 %0, %1, off sc0 sc1" : "=v"(r) : "v"(p) : "memory");
  return r;
}
__device__ __forceinline__ void st_b128_bypass(unsigned short* p, bf16x8 v) {
  asm volatile("global_store_dwordx4 %0, %1, off sc0 sc1" :: "v"(p), "v"(v) : "memory");
}
__device__ __forceinline__ unsigned ld_u32_bypass(const unsigned* p) {
  unsigned r;
  asm volatile("global_load_dword %0, %1, off sc0 sc1\n\ts_waitcnt vmcnt(0)"
               : "=v"(r) : "v"(p) : "memory");
  return r;
}
__device__ __forceinline__ bf16x8 ld_b128(const unsigned short* p) {
  bf16x8 r;
  asm volatile("global_load_dwordx4 %0, %1, off" : "=v"(r) : "v"(p) : "memory");
  return r;
}
#define WAITVM0() asm volatile("s_waitcnt vmcnt(0)" ::: "memory")

// JAX threefry2x32 (20 rounds)
__device__ __forceinline__ void tf2x32(unsigned k0, unsigned k1, unsigned x0, unsigned x1,
                                       unsigned &o0, unsigned &o1) {
  unsigned ks2 = k0 ^ k1 ^ 0x1BD11BDAu;
  x0 += k0; x1 += k1;
#define TFR(R) { x0 += x1; x1 = (x1 << R) | (x1 >> (32 - R)); x1 ^= x0; }
  TFR(13) TFR(15) TFR(26) TFR(6)   x0 += k1;  x1 += ks2 + 1u;
  TFR(17) TFR(29) TFR(16) TFR(24)  x0 += ks2; x1 += k0 + 2u;
  TFR(13) TFR(15) TFR(26) TFR(6)   x0 += k0;  x1 += k1 + 3u;
  TFR(17) TFR(29) TFR(16) TFR(24)  x0 += k1;  x1 += ks2 + 4u;
  TFR(13) TFR(15) TFR(26) TFR(6)   x0 += ks2; x1 += k0 + 5u;
#undef TFR
  o0 = x0; o1 = x1;
}

// ---- prep: swizzles, tables, masks, slot0, zero cnt --------------------------
__global__ void prep(const float* __restrict__ W_hh, const float* __restrict__ W1,
                     const float* __restrict__ emb,  const float* __restrict__ W_ih,
                     const float* __restrict__ b_ih, const float* __restrict__ b_hh,
                     const float* __restrict__ vision, const int* __restrict__ env_zeros,
                     const float* __restrict__ belief,
                     unsigned short* __restrict__ wBf, unsigned short* __restrict__ wQf,
                     float* __restrict__ girz, float* __restrict__ gin,
                     float* __restrict__ projP, unsigned char* __restrict__ maskb,
                     unsigned short* __restrict__ hbS, unsigned* __restrict__ cnt) {
  int b = blockIdx.x, tid = threadIdx.x;
  if (b < 768) {                               // wBf swizzle: coalesced read W_hh
    int idx = b * 256 + tid;
    int row = idx >> 7, k4 = (idx & 127) << 2;
    float4 v = *(const float4*)(W_hh + ((size_t)row << 9) + k4);
    int gam = row >> 9, sl = (row >> 6) & 7, q = (row >> 4) & 3, col0 = row & 15;
    int kt = k4 >> 5, quad = (k4 >> 3) & 3, e = k4 & 7;
    int F = (sl * 12 + gam * 4 + q) * 16 + kt;
    ushort4 o; o.x = f2b(v.x); o.y = f2b(v.y); o.z = f2b(v.z); o.w = f2b(v.w);
    *(ushort4*)(wBf + ((size_t)F << 9) + ((quad * 16 + col0) << 3) + e) = o;
  } else if (b < 784) {                        // wQf swizzle
    int idx = (b - 768) * 256 + tid;
    int f = idx >> 7, k4 = (idx & 127) << 2;
    float4 v = *(const float4*)(W1 + (size_t)f * 1024 + 512 + k4);
    int ft = f >> 4, col0 = f & 15;
    int kt = k4 >> 5, quad = (k4 >> 3) & 3, e = k4 & 7;
    int F = ft * 16 + kt;
    ushort4 o; o.x = f2b(v.x); o.y = f2b(v.y); o.z = f2b(v.z); o.w = f2b(v.w);
    *(ushort4*)(wQf + ((size_t)F << 9) + ((quad * 16 + col0) << 3) + e) = o;
  } else if (b < 816) {                        // girz[gam*8+a][512]
    int idx = (b - 784) * 256 + tid;
    int c = idx & 511, ga = idx >> 9;
    int a = ga & 7, gam = ga >> 3;
    float s = b_ih[gam * 512 + c] + b_hh[gam * 512 + c];
    if (a < 7) {
      #pragma unroll
      for (int k = 0; k < 4; ++k) s += emb[a * 4 + k] * W_ih[(gam * 512 + c) * 4 + k];
    }
    girz[idx] = s;
  } else if (b < 832) {                        // gin[a][512] = i_n (no b_hh)
    int idx = (b - 816) * 256 + tid;
    int c = idx & 511, a = idx >> 9;
    float s = b_ih[1024 + c];
    if (a < 7) {
      #pragma unroll
      for (int k = 0; k < 4; ++k) s += emb[a * 4 + k] * W_ih[(1024 + c) * 4 + k];
    }
    gin[idx] = s;
  } else if (b < 1088) {                       // projP[s][f] = vision[s] . W1a[f]
    int e = (b - 832) * 256 + tid;
    int s = e >> 5, f = e & 31;
    const float4* vr = (const float4*)(vision + (size_t)s * 512);
    const float4* wr = (const float4*)(W1 + (size_t)f * 1024);
    float a0 = 0.f, a1 = 0.f;
    for (int i = 0; i < 128; i += 2) {
      float4 x = vr[i], w = wr[i];
      float4 y = vr[i + 1], u = wr[i + 1];
      a0 += x.x * w.x + x.y * w.y + x.z * w.z + x.w * w.w;
      a1 += y.x * u.x + y.y * u.y + y.z * u.z + y.w * u.w;
    }
    projP[e] = a0 + a1;
  } else if (b < 1152) {                       // masks: legacy JAX threefry
    int i = (b - 1088) * 256 + tid;
    unsigned a0, b0, a1, b1_;
    tf2x32(0u, 42u, 0u, 2u, a0, b0);
    tf2x32(0u, 42u, 1u, 3u, a1, b1_);
    unsigned p0, p1, n0, n1;
    tf2x32(a0, a1, (unsigned)i, (unsigned)(i + 16384), p0, p1);
    tf2x32(b0, b1_, (unsigned)i, (unsigned)(i + 16384), n0, n1);
    #pragma unroll
    for (int h = 0; h < 2; ++h) {
      int f = i + h * 16384;
      unsigned pw = h ? p1 : p0, nw = h ? n1 : n0;
      int t = f >> 7, j = (f >> 3) & 15, nn = f & 7;
      int ok = (t + j < T_DIM - 1);
      if (ok) {
        int lo = t + 1, hi = t + j + 1, hit = 0;
        #pragma unroll
        for (int q = 0; q < 4; ++q) { int z = env_zeros[nn * 4 + q]; hit |= (z >= lo && z <= hi); }
        ok = !hit;
      }
      unsigned sp = ((pw >> 9) < 0xCCCCDu) ? 1u : 0u;
      unsigned sn = ((nw >> 9) < 0xCCCCDu) ? 2u : 0u;
      maskb[f] = ok ? (unsigned char)(sp | sn) : (unsigned char)0;
    }
  } else if (b == 1152) {                      // zero barrier counters
    for (int i = tid; i < 1024; i += 256) cnt[i] = 0u;
  } else {                                     // slot0: belief -> A-frag layout
    int i = (b - 1153) * 256 + tid;            // [0, 131072)
    int f = i >> 6, l = i & 63;
    int seq = (f >> 4) * 16 + (l & 15);
    int kb = (f & 15) * 32 + (l >> 4) * 8;
    const float* src = belief + (size_t)seq * 512 + kb;
    float4 v0 = *(const float4*)src, v1 = *(const float4*)(src + 4);
    bf16x8 o;
    o[0] = (short)f2b(v0.x); o[1] = (short)f2b(v0.y); o[2] = (short)f2b(v0.z); o[3] = (short)f2b(v0.w);
    o[4] = (short)f2b(v1.x); o[5] = (short)f2b(v1.y); o[6] = (short)f2b(v1.z); o[7] = (short)f2b(v1.w);
    *(bf16x8*)&hbS[((size_t)f << 9) + l * 8] = o;
  }
}

// ---- persistent GRU: 6 waves, balanced epilogue, hp in LDS -------------------
__global__ __launch_bounds__(384, 1) void gru_main(
    const float* __restrict__ belief, const int* __restrict__ actions,
    const float* __restrict__ b_hh, const unsigned short* __restrict__ wBf,
    const float* __restrict__ girz, const float* __restrict__ gin,
    unsigned short* __restrict__ hbS, unsigned* __restrict__ cnt) {
  __shared__ char smem[65536];                 // sA (64KB) | accL(48KB)+bounce
  __shared__ float hpL[64][68];                // fp32 h carry; static 82.9KB -> 1 wg/CU
  unsigned short* sA = (unsigned short*)smem;
  float* accL = (float*)smem;                  // alias, live after GEMM
  unsigned short* bounce = (unsigned short*)(smem + 49152);  // [64][72]

  const int tid = threadIdx.x, w = tid >> 6, lane = tid & 63;
  const int b = blockIdx.x;
  const int sl = b >> 5, g = b & 31;
  const int c0 = sl * 64, seqbase = g * 64;

  // B fragments: 2 N-tiles per wave, register-resident
  bf16x8 bB[32];
  {
    const unsigned short* p0 = wBf + ((size_t)((sl * 12 + 2 * w) * 16) << 9) + lane * 8;
    #pragma unroll
    for (int kt = 0; kt < 32; ++kt) bB[kt] = ld_b128(p0 + ((size_t)kt << 9));
    WAITVM0();
  }

  // hp init: each thread owns the same (s,c) elements it updates later
  #pragma unroll
  for (int k = 0; k < 11; ++k) {
    int e = tid + 384 * k;
    if (e < 4096) {
      int s = e >> 6, c = e & 63;
      hpL[s][c] = belief[((size_t)(seqbase + s) << 9) + c0 + c];
    }
  }

  for (int j = 0; j < KK; ++j) {
    if (j > 0) {                               // group barrier
      if (tid == 0) {
        const unsigned tgt = 8u * (unsigned)j;
        while (ld_u32_bypass(cnt + g * 32) < tgt) __builtin_amdgcn_s_sleep(1);
      }
      __syncthreads();
    }
    // stage h_j, sl-rotated line order to spread L3 bank/line pressure
    {
      const unsigned short* src = hbS + (size_t)j * SLOT + ((size_t)(g * 64) << 9);
      int line[11];
      bf16x8 tv[11];
      #pragma unroll
      for (int k = 0; k < 11; ++k) line[k] = ((tid + 384 * k) + sl * 512) & 4095;
      #pragma unroll
      for (int k = 0; k < 10; ++k) tv[k] = ld_b128_bypass(src + ((size_t)line[k] << 3));
      const bool ex = (tid < 256);
      if (ex) tv[10] = ld_b128_bypass(src + ((size_t)line[10] << 3));
      WAITVM0();
      #pragma unroll
      for (int k = 0; k < 10; ++k) *(bf16x8*)&sA[(size_t)line[k] << 3] = tv[k];
      if (ex) *(bf16x8*)&sA[(size_t)line[10] << 3] = tv[10];
    }
    __syncthreads();

    // GEMM: 128 MFMA per wave
    f32x4 acc[4][2];
    #pragma unroll
    for (int a = 0; a < 4; ++a) { acc[a][0] = (f32x4){0,0,0,0}; acc[a][1] = (f32x4){0,0,0,0}; }
    #pragma unroll
    for (int kt = 0; kt < 16; ++kt) {
      #pragma unroll
      for (int a = 0; a < 4; ++a) {
        bf16x8 af = *(const bf16x8*)&sA[((a * 16 + kt) << 9) + (lane << 3)];
        acc[a][0] = MFMA16(af, bB[kt], acc[a][0]);
        acc[a][1] = MFMA16(af, bB[16 + kt], acc[a][1]);
      }
    }
    __syncthreads();   // sA dead; accL/bounce alias live

    // all 6 waves publish both N-tiles
    #pragma unroll
    for (int t2 = 0; t2 < 2; ++t2)
      #pragma unroll
      for (int a = 0; a < 4; ++a)
        *(f32x4*)&accL[(((w * 2 + t2) * 4 + a) * 64 + lane) * 4] = acc[a][t2];
    __syncthreads();

    // balanced epilogue: 4096 elements over 384 threads
    #pragma unroll
    for (int k = 0; k < 11; ++k) {
      int e = tid + 384 * k;
      if (e < 4096) {
        int s = e >> 6, c = e & 63;
        int q = c >> 4, a = s >> 4, m = s & 15;
        int li = (((m >> 2) * 16 + (c & 15)) << 2) + (m & 3);
        float aR = accL[((q * 4 + a) << 8) + li];
        float aZ = accL[(((4 + q) * 4 + a) << 8) + li];
        float aN = accL[(((8 + q) * 4 + a) << 8) + li];
        int seq = seqbase + s;
        int tr = seq >> 3, nn = seq & 7, tj = tr + j;
        int ai = (tj < T_DIM) ? actions[tj * 8 + nn] : 7;
        int cc = c0 + c;
        float rg = 1.f / (1.f + __expf(-(aR + girz[(ai << 9) + cc])));
        float zg = 1.f / (1.f + __expf(-(aZ + girz[((8 + ai) << 9) + cc])));
        float pre = gin[(ai << 9) + cc] + rg * (aN + b_hh[1024 + cc]);
        float cand = 1.f - 2.f / (1.f + __expf(2.f * pre));
        float hn = (1.f - zg) * cand + zg * hpL[s][c];
        hpL[s][c] = hn;
        bounce[s * 72 + c] = f2b(hn);
      }
    }
    __syncthreads();

    // publish our slice's h_{j+1} frags to slot j+1 (write-through L3)
    unsigned short* dst = hbS + (size_t)(j + 1) * SLOT;
    {
      int f = tid >> 6, l = tid & 63;
      int a = f >> 1, ktl = f & 1;
      bf16x8 v = *(const bf16x8*)&bounce[(16 * a + (l & 15)) * 72 + 32 * ktl + (l >> 4) * 8];
      st_b128_bypass(&dst[((size_t)(g * 64 + a * 16 + sl * 2 + ktl) << 9) + (l << 3)], v);
      if (tid < 128) {
        int i2 = tid + 384;
        int f2 = i2 >> 6, l2 = i2 & 63;
        int a2 = f2 >> 1, ktl2 = f2 & 1;
        bf16x8 v2 = *(const bf16x8*)&bounce[(16 * a2 + (l2 & 15)) * 72 + 32 * ktl2 + (l2 >> 4) * 8];
        st_b128_bypass(&dst[((size_t)(g * 64 + a2 * 16 + sl * 2 + ktl2) << 9) + (l2 << 3)], v2);
      }
    }
    WAITVM0();
    __syncthreads();
    if (tid == 0) atomicAdd(cnt + g * 32, 1u);
  }
}

// ---- classifier + loss: 512 blocks x 4 waves, atomic-free --------------------
__global__ __launch_bounds__(256, 1) void cls(
    const unsigned short* __restrict__ hbS, const unsigned short* __restrict__ wQf,
    const int* __restrict__ neg_inds, const float* __restrict__ b1,
    const float* __restrict__ W2, const float* __restrict__ b2,
    const float* __restrict__ projP, const unsigned char* __restrict__ maskb,
    float* __restrict__ parts) {
  __shared__ float red[4][4];
  const int g = blockIdx.x >> 4, jq = blockIdx.x & 15;
  const int w = threadIdx.x >> 6, lane = threadIdx.x & 63;
  const int col0 = lane & 15, quad = lane >> 4;
  const int a = w, j = jq + 1;
  const unsigned short* hsrc = hbS + (size_t)j * SLOT + ((size_t)(g * 64 + a * 16) << 9);
  const unsigned short* qp = wQf + lane * 8;
  f32x4 acc0 = {0,0,0,0}, acc1 = {0,0,0,0};
  #pragma unroll
  for (int kt = 0; kt < 16; ++kt) {
    bf16x8 af = *(const bf16x8*)&hsrc[((size_t)kt << 9) + lane * 8];
    acc0 = MFMA16(af, *(const bf16x8*)(qp + ((size_t)kt << 9)), acc0);
    acc1 = MFMA16(af, *(const bf16x8*)(qp + ((size_t)(16 + kt) << 9)), acc1);
  }
  float b1v0 = b1[col0], b1v1 = b1[col0 + 16];
  float w2v0 = W2[col0], w2v1 = W2[col0 + 16], b2v = b2[0];
  float wj = (jq == 0) ? 5.f : (jq == 1) ? 4.f : (jq < 4) ? 3.f : (jq < 8) ? 2.f : 1.f;
  float sumP = 0.f, cntP = 0.f, sumN = 0.f, cntN = 0.f;
  #pragma unroll
  for (int r = 0; r < 4; ++r) {
    int seq = g * 64 + 16 * a + quad * 4 + r;
    int t = seq >> 3, nn = seq & 7;
    unsigned mb = maskb[(t << 7) + (jq << 3) + nn];
    float pp0 = 0.f, pp1 = 0.f, pn0 = 0.f, pn1 = 0.f;
    if (mb) {
      int sp = seq + j * 8;
      pp0 = projP[(sp << 5) + col0];  pp1 = projP[(sp << 5) + 16 + col0];
      int ni = neg_inds[sp];
      pn0 = projP[(ni << 5) + col0];  pn1 = projP[(ni << 5) + 16 + col0];
    }
    float a0v = acc0[r] + b1v0, a1v = acc1[r] + b1v1;
    float pl = fmaxf(a0v + pp0, 0.f) * w2v0 + fmaxf(a1v + pp1, 0.f) * w2v1;
    float nl = fmaxf(a0v + pn0, 0.f) * w2v0 + fmaxf(a1v + pn1, 0.f) * w2v1;
    #pragma unroll
    for (int d = 1; d < 16; d <<= 1) { pl += __shfl_xor(pl, d, 64); nl += __shfl_xor(nl, d, 64); }
    if (col0 == 0 && mb) {
      if (mb & 1u) {
        float x = -(pl + b2v);
        sumP += wj * (fmaxf(x, 0.f) + __logf(1.f + __expf(-fabsf(x))));
        cntP += 1.f;
      }
      if (mb & 2u) {
        float x = (nl + b2v);
        sumN += wj * (fmaxf(x, 0.f) + __logf(1.f + __expf(-fabsf(x))));
        cntN += 1.f;
      }
    }
  }
  #pragma unroll
  for (int d = 16; d < 64; d <<= 1) {
    sumP += __shfl_xor(sumP, d, 64); cntP += __shfl_xor(cntP, d, 64);
    sumN += __shfl_xor(sumN, d, 64); cntN += __shfl_xor(cntN, d, 64);
  }
  if (lane == 0) { red[w][0] = sumP; red[w][1] = cntP; red[w][2] = sumN; red[w][3] = cntN; }
  __syncthreads();
  if (threadIdx.x < 4)
    parts[blockIdx.x * 4 + threadIdx.x] =
        red[0][threadIdx.x] + red[1][threadIdx.x] + red[2][threadIdx.x] + red[3][threadIdx.x];
}

__global__ __launch_bounds__(256, 1) void fin(const float* __restrict__ parts,
                                              float* __restrict__ out) {
  __shared__ float red[4][4];
  const int tid = threadIdx.x;
  float v0 = 0.f, v1 = 0.f, v2 = 0.f, v3 = 0.f;
  for (int i = tid; i < 512; i += 256) {
    v0 += parts[i * 4 + 0]; v1 += parts[i * 4 + 1];
    v2 += parts[i * 4 + 2]; v3 += parts[i * 4 + 3];
  }
  #pragma unroll
  for (int d = 1; d < 64; d <<= 1) {
    v0 += __shfl_xor(v0, d, 64); v1 += __shfl_xor(v1, d, 64);
    v2 += __shfl_xor(v2, d, 64); v3 += __shfl_xor(v3, d, 64);
  }
  if ((tid & 63) == 0) {
    int w = tid >> 6;
    red[w][0] = v0; red[w][1] = v1; red[w][2] = v2; red[w][3] = v3;
  }
  __syncthreads();
  if (tid == 0) {
    float sP = red[0][0] + red[1][0] + red[2][0] + red[3][0];
    float cP = red[0][1] + red[1][1] + red[2][1] + red[3][1];
    float sN = red[0][2] + red[1][2] + red[2][2] + red[3][2];
    float cN = red[0][3] + red[1][3] + red[2][3] + red[3][3];
    out[0] = (sP / fmaxf(cP, 1.f) + sN / fmaxf(cN, 1.f)) * 0.1f;
  }
}

extern "C" void kernel_launch(void* const* d_in, const int* in_sizes, int n_in,
                              void* d_out, int out_size, void* d_ws, size_t ws_size,
                              hipStream_t stream) {
  const float* vision  = (const float*)d_in[0];
  const float* belief  = (const float*)d_in[1];
  const int*   actions = (const int*)d_in[2];
  const int*   envz    = (const int*)d_in[3];
  const int*   negi    = (const int*)d_in[4];
  const float* emb     = (const float*)d_in[5];
  const float* W_ih    = (const float*)d_in[6];
  const float* W_hh    = (const float*)d_in[7];
  const float* b_ih    = (const float*)d_in[8];
  const float* b_hh    = (const float*)d_in[9];
  const float* W1      = (const float*)d_in[10];
  const float* b1      = (const float*)d_in[11];
  const float* W2      = (const float*)d_in[12];
  const float* b2      = (const float*)d_in[13];

  char* ws = (char*)d_ws;
  unsigned*       cnt   = (unsigned*)(ws + 0);               // 32 groups x 32 ints (4KB)
  float*          parts = (float*)(ws + 4096);               // 512 x 4 floats (8KB)
  unsigned short* wBf   = (unsigned short*)(ws + 12288);     // 1572864 B
  unsigned short* wQf   = (unsigned short*)(ws + 1585152);   // 32768 B
  float*          girz  = (float*)(ws + 1617920);            // 32768 B
  float*          gin   = (float*)(ws + 1650688);            // 16384 B
  float*          projP = (float*)(ws + 1667072);            // 262144 B
  unsigned char*  maskb = (unsigned char*)(ws + 1929216);    // 32768 B
  unsigned short* hbS   = (unsigned short*)(ws + 1961984);   // 17 x 2097152 B

  prep<<<1665, 256, 0, stream>>>(W_hh, W1, emb, W_ih, b_ih, b_hh, vision, envz,
                                 belief, wBf, wQf, girz, gin, projP, maskb,
                                 hbS, cnt);
  gru_main<<<256, 384, 0, stream>>>(belief, actions, b_hh, wBf, girz, gin,
                                    hbS, cnt);
  cls<<<512, 256, 0, stream>>>(hbS, wQf, negi, b1, W2, b2, projP, maskb, parts);
  fin<<<1, 256, 0, stream>>>(parts, (float*)d_out);
}